// Round 1
// baseline (3189.639 us; speedup 1.0000x reference)
//
#include <hip/hip_runtime.h>
#include <math.h>

#define EPS 1e-5f

// L=4, B=16, N=8, P=64, D=128, F=128, H=8
// M = B*N*P = 8192 rows, HF = 1024, QKV width = 3072

__device__ __forceinline__ float gelu_f(float x) {
    return 0.5f * x * (1.0f + erff(x * 0.7071067811865476f));
}

// ---------------------------------------------------------------------------
// Kernel 1: y = LN(x @ W^T + b) * s + t      (x: (M,128), W: (128,128))
// one block per row, 128 threads (one per output col)
// ---------------------------------------------------------------------------
__global__ __launch_bounds__(128) void lin128_ln(
    const float* __restrict__ x, const float* __restrict__ W,
    const float* __restrict__ bias, const float* __restrict__ lns,
    const float* __restrict__ lnb, float* __restrict__ y)
{
    int row = blockIdx.x;
    int c = threadIdx.x;
    __shared__ __align__(16) float xs[128];
    __shared__ float red[2];
    xs[c] = x[(size_t)row * 128 + c];
    __syncthreads();
    float acc = bias[c];
    const float4* w4 = (const float4*)(W + (size_t)c * 128);
    const float4* x4 = (const float4*)xs;
#pragma unroll
    for (int k = 0; k < 32; ++k) {
        float4 wv = w4[k]; float4 xv = x4[k];
        acc = fmaf(wv.x, xv.x, acc); acc = fmaf(wv.y, xv.y, acc);
        acc = fmaf(wv.z, xv.z, acc); acc = fmaf(wv.w, xv.w, acc);
    }
    float v = acc, sum = v;
#pragma unroll
    for (int o = 32; o > 0; o >>= 1) sum += __shfl_down(sum, o, 64);
    int lane = c & 63, w = c >> 6;
    if (lane == 0) red[w] = sum;
    __syncthreads();
    float mean = (red[0] + red[1]) * (1.0f / 128.0f);
    __syncthreads();
    float d = v - mean, sq = d * d;
#pragma unroll
    for (int o = 32; o > 0; o >>= 1) sq += __shfl_down(sq, o, 64);
    if (lane == 0) red[w] = sq;
    __syncthreads();
    float var = (red[0] + red[1]) * (1.0f / 128.0f);
    y[(size_t)row * 128 + c] = d * rsqrtf(var + EPS) * lns[c] + lnb[c];
}

// ---------------------------------------------------------------------------
// Kernel 2: dual QKV GEMM + sigmoid-alpha blend, scatter to (B,N,H,P,F)
// tile: 64 rows x 64 cols, K=128. 256 threads.
// thread: rows r = tr*8 + i (i<8), cols c = tc + 32*j (j<2);  tc=t&31, tr=t>>5
// ---------------------------------------------------------------------------
__global__ __launch_bounds__(256) void qkv_blend(
    const float* __restrict__ xc_g, const float* __restrict__ xp_g,
    const float* __restrict__ Wc, const float* __restrict__ bc,
    const float* __restrict__ Wp, const float* __restrict__ bp,
    const float* __restrict__ alpha,   // (3,1024) slice for this layer
    float* __restrict__ Q, float* __restrict__ K, float* __restrict__ V)
{
    __shared__ __align__(16) float xc[64][128];
    __shared__ __align__(16) float xp[64][128];
    __shared__ float wc[64][129];
    __shared__ float wp[64][129];
    int R = blockIdx.x * 64;
    int C = blockIdx.y * 64;
    int t = threadIdx.x;

    // stage x tiles (float4, coalesced)
#pragma unroll
    for (int i = 0; i < 8; ++i) {
        int lin = t + i * 256;          // [0,2048)
        int r = lin >> 5, k4 = lin & 31;
        *((float4*)&xc[r][k4 * 4]) = ((const float4*)(xc_g + (size_t)(R + r) * 128))[k4];
        *((float4*)&xp[r][k4 * 4]) = ((const float4*)(xp_g + (size_t)(R + r) * 128))[k4];
    }
    // stage W tiles (scalar store, pad 129)
#pragma unroll
    for (int i = 0; i < 8; ++i) {
        int lin = t + i * 256;          // [0,2048)
        int r = lin >> 5, k4 = lin & 31;
        float4 wv = ((const float4*)(Wc + (size_t)(C + r) * 128))[k4];
        wc[r][k4 * 4 + 0] = wv.x; wc[r][k4 * 4 + 1] = wv.y;
        wc[r][k4 * 4 + 2] = wv.z; wc[r][k4 * 4 + 3] = wv.w;
        float4 pv = ((const float4*)(Wp + (size_t)(C + r) * 128))[k4];
        wp[r][k4 * 4 + 0] = pv.x; wp[r][k4 * 4 + 1] = pv.y;
        wp[r][k4 * 4 + 2] = pv.z; wp[r][k4 * 4 + 3] = pv.w;
    }
    __syncthreads();

    int tc = t & 31, tr = t >> 5;
    float ac[8][2] = {{0}}, ap[8][2] = {{0}};
#pragma unroll 4
    for (int k = 0; k < 128; ++k) {
        float w0 = wc[tc][k],      w1 = wc[tc + 32][k];
        float p0 = wp[tc][k],      p1 = wp[tc + 32][k];
#pragma unroll
        for (int i = 0; i < 8; ++i) {
            float xcv = xc[tr * 8 + i][k];
            float xpv = xp[tr * 8 + i][k];
            ac[i][0] = fmaf(xcv, w0, ac[i][0]);
            ac[i][1] = fmaf(xcv, w1, ac[i][1]);
            ap[i][0] = fmaf(xpv, p0, ap[i][0]);
            ap[i][1] = fmaf(xpv, p1, ap[i][1]);
        }
    }

#pragma unroll
    for (int j = 0; j < 2; ++j) {
        int col = C + tc + 32 * j;          // [0,3072)
        int qkv = col >> 10, hf = col & 1023;
        int h = hf >> 7, f = hf & 127;
        float a = 1.0f / (1.0f + expf(-alpha[qkv * 1024 + hf]));
        float bcv = bc[col], bpv = bp[col];
        float* out = (qkv == 0) ? Q : ((qkv == 1) ? K : V);
#pragma unroll
        for (int i = 0; i < 8; ++i) {
            int row = R + tr * 8 + i;       // = bn*64 + p
            int bn = row >> 6, p = row & 63;
            float val = a * (ac[i][j] + bcv) + (1.0f - a) * (ap[i][j] + bpv);
            out[(size_t)((bn * 8 + h) * 64 + p) * 128 + f] = val;
        }
    }
}

// ---------------------------------------------------------------------------
// Kernel 3: attention per (b,n,h): softmax(QK^T * scale) @ V, then LN(bn1),
// written directly in (B,N,P,H*F) transposed layout.
// 256 threads: thread t -> row p = t>>2, quarter qo = t&3
// ---------------------------------------------------------------------------
__global__ __launch_bounds__(256) void attn_ln(
    const float* __restrict__ Q, const float* __restrict__ K,
    const float* __restrict__ V,
    const float* __restrict__ bn1s, const float* __restrict__ bn1b,
    float* __restrict__ At)
{
    int g = blockIdx.x;             // bn*8 + h
    int bn = g >> 3, h = g & 7;
    const float* Qg = Q + (size_t)g * 8192;
    const float* Kg = K + (size_t)g * 8192;
    const float* Vg = V + (size_t)g * 8192;
    __shared__ __align__(16) float Qs[64][132];
    __shared__ __align__(16) float Ks[64][132];
    __shared__ __align__(16) float Vs[64][132];
    __shared__ float Ss[64][68];
    int t = threadIdx.x;
#pragma unroll
    for (int i = 0; i < 8; ++i) {
        int lin = t + i * 256;      // [0,2048) float4s
        int r = lin >> 5, k4 = lin & 31;
        *((float4*)&Qs[r][k4 * 4]) = ((const float4*)Qg)[lin];
        *((float4*)&Ks[r][k4 * 4]) = ((const float4*)Kg)[lin];
        *((float4*)&Vs[r][k4 * 4]) = ((const float4*)Vg)[lin];
    }
    __syncthreads();

    int p = t >> 2, qo = t & 3;
    const float scale = 0.08838834764831845f;   // 128^-0.5
    float sv[16];
#pragma unroll
    for (int j = 0; j < 16; ++j) {
        int q = qo + 4 * j;
        float acc = 0.0f;
#pragma unroll 4
        for (int k = 0; k < 128; ++k) acc = fmaf(Qs[p][k], Ks[q][k], acc);
        sv[j] = acc * scale;
    }
    // softmax over row p (4 lanes per row)
    float mx = sv[0];
#pragma unroll
    for (int j = 1; j < 16; ++j) mx = fmaxf(mx, sv[j]);
    mx = fmaxf(mx, __shfl_xor(mx, 1, 4));
    mx = fmaxf(mx, __shfl_xor(mx, 2, 4));
    float sum = 0.0f;
#pragma unroll
    for (int j = 0; j < 16; ++j) { sv[j] = expf(sv[j] - mx); sum += sv[j]; }
    sum += __shfl_xor(sum, 1, 4);
    sum += __shfl_xor(sum, 2, 4);
    float inv = 1.0f / sum;
#pragma unroll
    for (int j = 0; j < 16; ++j) Ss[p][qo + 4 * j] = sv[j] * inv;
    __syncthreads();

    // A = attn @ V ; thread covers f = qo + 4*i, i<32
    float av[32];
#pragma unroll
    for (int i = 0; i < 32; ++i) {
        int f = qo + 4 * i;
        float acc = 0.0f;
#pragma unroll 4
        for (int q = 0; q < 64; ++q) acc = fmaf(Ss[p][q], Vs[q][f], acc);
        av[i] = acc;
    }
    // LN over f (128) within the 4-lane row group
    float s1 = 0.0f;
#pragma unroll
    for (int i = 0; i < 32; ++i) s1 += av[i];
    s1 += __shfl_xor(s1, 1, 4);
    s1 += __shfl_xor(s1, 2, 4);
    float mean = s1 * (1.0f / 128.0f);
    float s2 = 0.0f;
#pragma unroll
    for (int i = 0; i < 32; ++i) { float d = av[i] - mean; s2 += d * d; }
    s2 += __shfl_xor(s2, 1, 4);
    s2 += __shfl_xor(s2, 2, 4);
    float rs = rsqrtf(s2 * (1.0f / 128.0f) + EPS);

    float* orow = At + (size_t)(bn * 64 + p) * 1024 + h * 128;
#pragma unroll
    for (int i = 0; i < 32; ++i) {
        int f = qo + 4 * i;
        orow[f] = (av[i] - mean) * rs * bn1s[f] + bn1b[f];
    }
}

// ---------------------------------------------------------------------------
// Kernel 4: proj GEMM (K=1024) + bn2 LN + gelu(cur) residual + ln_o LN -> O_hat
// tile: 16 rows x 128 cols, 256 threads; K chunked by 128.
// thread: rows r = tr*2 + i (i<2), cols c = tc + 32*j (j<4)
// ---------------------------------------------------------------------------
__global__ __launch_bounds__(256) void proj_ln(
    const float* __restrict__ At_g, const float* __restrict__ W,
    const float* __restrict__ bias,
    const float* __restrict__ bn2s, const float* __restrict__ bn2b,
    const float* __restrict__ lnos, const float* __restrict__ lnob,
    const float* __restrict__ cur, float* __restrict__ Ohat)
{
    __shared__ float Wt[128][129];
    __shared__ __align__(16) float Ats[16][132];
    int R = blockIdx.x * 16;
    int t = threadIdx.x;
    int tc = t & 31, tr = t >> 5;
    float acc[2][4] = {{0}};

    for (int kc = 0; kc < 8; ++kc) {
#pragma unroll
        for (int i = 0; i < 16; ++i) {
            int lin = t + i * 256;      // [0,4096) float4s
            int r = lin >> 5, k4 = lin & 31;
            float4 wv = ((const float4*)(W + (size_t)r * 1024 + kc * 128))[k4];
            Wt[r][k4 * 4 + 0] = wv.x; Wt[r][k4 * 4 + 1] = wv.y;
            Wt[r][k4 * 4 + 2] = wv.z; Wt[r][k4 * 4 + 3] = wv.w;
        }
#pragma unroll
        for (int i = 0; i < 2; ++i) {
            int lin = t + i * 256;      // [0,512)
            int r = lin >> 5, k4 = lin & 31;
            *((float4*)&Ats[r][k4 * 4]) =
                ((const float4*)(At_g + (size_t)(R + r) * 1024 + kc * 128))[k4];
        }
        __syncthreads();
#pragma unroll 4
        for (int k = 0; k < 128; ++k) {
            float a0 = Ats[tr * 2][k], a1 = Ats[tr * 2 + 1][k];
#pragma unroll
            for (int j = 0; j < 4; ++j) {
                float w = Wt[tc + 32 * j][k];
                acc[0][j] = fmaf(a0, w, acc[0][j]);
                acc[1][j] = fmaf(a1, w, acc[1][j]);
            }
        }
        __syncthreads();
    }

#pragma unroll
    for (int i = 0; i < 2; ++i) {
        int row = R + tr * 2 + i;
        float vals[4];
        float part = 0.0f;
#pragma unroll
        for (int j = 0; j < 4; ++j) { vals[j] = acc[i][j] + bias[tc + 32 * j]; part += vals[j]; }
        float s = part;
#pragma unroll
        for (int m = 1; m < 32; m <<= 1) s += __shfl_xor(s, m, 32);
        float mean = s * (1.0f / 128.0f);
        float sq = 0.0f;
#pragma unroll
        for (int j = 0; j < 4; ++j) { float d = vals[j] - mean; sq += d * d; }
#pragma unroll
        for (int m = 1; m < 32; m <<= 1) sq += __shfl_xor(sq, m, 32);
        float rs = rsqrtf(sq * (1.0f / 128.0f) + EPS);

        float opre[4];
        float part2 = 0.0f;
#pragma unroll
        for (int j = 0; j < 4; ++j) {
            int c = tc + 32 * j;
            float ynorm = (vals[j] - mean) * rs * bn2s[c] + bn2b[c];
            float cv = cur[(size_t)row * 128 + c];
            float a2 = ynorm + gelu_f(cv);
            opre[j] = cv + a2;
            part2 += opre[j];
        }
        float s2 = part2;
#pragma unroll
        for (int m = 1; m < 32; m <<= 1) s2 += __shfl_xor(s2, m, 32);
        float mean2 = s2 * (1.0f / 128.0f);
        float sq2 = 0.0f;
#pragma unroll
        for (int j = 0; j < 4; ++j) { float d = opre[j] - mean2; sq2 += d * d; }
#pragma unroll
        for (int m = 1; m < 32; m <<= 1) sq2 += __shfl_xor(sq2, m, 32);
        float rs2 = rsqrtf(sq2 * (1.0f / 128.0f) + EPS);
#pragma unroll
        for (int j = 0; j < 4; ++j) {
            int c = tc + 32 * j;
            Ohat[(size_t)row * 128 + c] = (opre[j] - mean2) * rs2 * lnos[c] + lnob[c];
        }
    }
}

// ---------------------------------------------------------------------------
// Kernel 5: cur = x @ ffn_w^T + ffn_b + gelu(x)
// ---------------------------------------------------------------------------
__global__ __launch_bounds__(128) void ffn_gelu(
    const float* __restrict__ x, const float* __restrict__ W,
    const float* __restrict__ bias, float* __restrict__ y)
{
    int row = blockIdx.x;
    int c = threadIdx.x;
    __shared__ __align__(16) float xs[128];
    float xv = x[(size_t)row * 128 + c];
    xs[c] = xv;
    __syncthreads();
    float acc = bias[c];
    const float4* w4 = (const float4*)(W + (size_t)c * 128);
    const float4* x4 = (const float4*)xs;
#pragma unroll
    for (int k = 0; k < 32; ++k) {
        float4 wv = w4[k]; float4 xq = x4[k];
        acc = fmaf(wv.x, xq.x, acc); acc = fmaf(wv.y, xq.y, acc);
        acc = fmaf(wv.z, xq.z, acc); acc = fmaf(wv.w, xq.w, acc);
    }
    y[(size_t)row * 128 + c] = acc + gelu_f(xv);
}

// ---------------------------------------------------------------------------
extern "C" void kernel_launch(void* const* d_in, const int* in_sizes, int n_in,
                              void* d_out, int out_size, void* d_ws, size_t ws_size,
                              hipStream_t stream)
{
    const float* seq       = (const float*)d_in[0];
    const float* Hpre      = (const float*)d_in[1];
    const float* pro1_w    = (const float*)d_in[2];
    const float* pro1_b    = (const float*)d_in[3];
    const float* pro2_w    = (const float*)d_in[4];
    const float* pro2_b    = (const float*)d_in[5];
    const float* ln_cur_s  = (const float*)d_in[6];
    const float* ln_cur_b  = (const float*)d_in[7];
    const float* ln_pre_s  = (const float*)d_in[8];
    const float* ln_pre_b  = (const float*)d_in[9];
    const float* cur_qkv_w = (const float*)d_in[10];
    const float* cur_qkv_b = (const float*)d_in[11];
    const float* pre_qkv_w = (const float*)d_in[12];
    const float* pre_qkv_b = (const float*)d_in[13];
    const float* alpha     = (const float*)d_in[14];
    const float* proj_w    = (const float*)d_in[15];
    const float* proj_b    = (const float*)d_in[16];
    const float* bn1_s     = (const float*)d_in[17];
    const float* bn1_b     = (const float*)d_in[18];
    const float* bn2_s     = (const float*)d_in[19];
    const float* bn2_b     = (const float*)d_in[20];
    const float* ln_o_s    = (const float*)d_in[21];
    const float* ln_o_b    = (const float*)d_in[22];
    const float* ffn_w     = (const float*)d_in[23];
    const float* ffn_b     = (const float*)d_in[24];

    float* ws = (float*)d_ws;
    const size_t MF  = (size_t)8192 * 128;    // 1,048,576
    const size_t MHF = (size_t)8192 * 1024;   // 8,388,608
    float* pre  = ws;
    float* cur  = ws + MF;
    float* Ohat = ws + 2 * MF;
    float* Atb  = ws + 3 * MF;
    float* Qb   = ws + 3 * MF + MHF;
    float* Kb   = Qb + MHF;
    float* Vb   = Kb + MHF;

    for (int l = 0; l < 4; ++l) {
        if (l == 0) {
            lin128_ln<<<8192, 128, 0, stream>>>(seq, pro1_w, pro1_b,
                                                ln_cur_s, ln_cur_b, cur);
        }
        lin128_ln<<<8192, 128, 0, stream>>>(Hpre + (size_t)l * MF,
                                            pro2_w + (size_t)l * 16384,
                                            pro2_b + l * 128,
                                            ln_pre_s + l * 128, ln_pre_b + l * 128, pre);
        qkv_blend<<<dim3(128, 48), 256, 0, stream>>>(
            cur, pre,
            cur_qkv_w + (size_t)l * 3072 * 128, cur_qkv_b + l * 3072,
            pre_qkv_w + (size_t)l * 3072 * 128, pre_qkv_b + l * 3072,
            alpha + l * 3 * 1024, Qb, Kb, Vb);
        attn_ln<<<1024, 256, 0, stream>>>(Qb, Kb, Vb,
                                          bn1_s + l * 128, bn1_b + l * 128, Atb);
        proj_ln<<<512, 256, 0, stream>>>(Atb,
                                         proj_w + (size_t)l * 128 * 1024,
                                         proj_b + l * 128,
                                         bn2_s + l * 128, bn2_b + l * 128,
                                         ln_o_s + l * 128, ln_o_b + l * 128,
                                         cur, Ohat);
        float* outp = (l == 3) ? (float*)d_out : cur;
        ffn_gelu<<<8192, 128, 0, stream>>>(Ohat,
                                           ffn_w + (size_t)l * 16384,
                                           ffn_b + l * 128, outp);
    }
}

// Round 2
// 1996.422 us; speedup vs baseline: 1.5977x; 1.5977x over previous
//
#include <hip/hip_runtime.h>
#include <math.h>

#define EPS 1e-5f

// L=4, B=16, N=8, P=64, D=128, F=128, H=8
// M = B*N*P = 8192 rows, HF = 1024, QKV width = 3072

typedef __bf16 bf16x8 __attribute__((ext_vector_type(8)));
typedef float f32x4 __attribute__((ext_vector_type(4)));

__device__ __forceinline__ float gelu_f(float x) {
    return 0.5f * x * (1.0f + erff(x * 0.7071067811865476f));
}

// convert 8 consecutive floats -> 8 bf16, store 16B to (swizzled) LDS slot
__device__ __forceinline__ void cvt_store8(void* dst, const float* __restrict__ src) {
    float4 a = ((const float4*)src)[0];
    float4 b = ((const float4*)src)[1];
    bf16x8 v;
    v[0] = (__bf16)a.x; v[1] = (__bf16)a.y; v[2] = (__bf16)a.z; v[3] = (__bf16)a.w;
    v[4] = (__bf16)b.x; v[5] = (__bf16)b.y; v[6] = (__bf16)b.z; v[7] = (__bf16)b.w;
    *(bf16x8*)dst = v;
}

// LDS tile layout: [64 or 128 rows][128 k] bf16, XOR-swizzled within row:
// element index = row*128 + (k ^ ((row&7)<<3));  k0 multiples of 8 stay 16B-aligned
__device__ __forceinline__ int swz(int row, int k0) {
    return row * 128 + (k0 ^ ((row & 7) << 3));
}
__device__ __forceinline__ bf16x8 ld_frag(const unsigned short* tile, int row, int k0) {
    return *(const bf16x8*)&tile[swz(row, k0)];
}

// ---------------------------------------------------------------------------
// Kernel 1: y = LN(x @ W^T + b) * s + t      (x: (M,128), W: (128,128))
// ---------------------------------------------------------------------------
__global__ __launch_bounds__(128) void lin128_ln(
    const float* __restrict__ x, const float* __restrict__ W,
    const float* __restrict__ bias, const float* __restrict__ lns,
    const float* __restrict__ lnb, float* __restrict__ y)
{
    int row = blockIdx.x;
    int c = threadIdx.x;
    __shared__ __align__(16) float xs[128];
    __shared__ float red[2];
    xs[c] = x[(size_t)row * 128 + c];
    __syncthreads();
    float acc = bias[c];
    const float4* w4 = (const float4*)(W + (size_t)c * 128);
    const float4* x4 = (const float4*)xs;
#pragma unroll
    for (int k = 0; k < 32; ++k) {
        float4 wv = w4[k]; float4 xv = x4[k];
        acc = fmaf(wv.x, xv.x, acc); acc = fmaf(wv.y, xv.y, acc);
        acc = fmaf(wv.z, xv.z, acc); acc = fmaf(wv.w, xv.w, acc);
    }
    float v = acc, sum = v;
#pragma unroll
    for (int o = 32; o > 0; o >>= 1) sum += __shfl_down(sum, o, 64);
    int lane = c & 63, w = c >> 6;
    if (lane == 0) red[w] = sum;
    __syncthreads();
    float mean = (red[0] + red[1]) * (1.0f / 128.0f);
    __syncthreads();
    float d = v - mean, sq = d * d;
#pragma unroll
    for (int o = 32; o > 0; o >>= 1) sq += __shfl_down(sq, o, 64);
    if (lane == 0) red[w] = sq;
    __syncthreads();
    float var = (red[0] + red[1]) * (1.0f / 128.0f);
    y[(size_t)row * 128 + c] = d * rsqrtf(var + EPS) * lns[c] + lnb[c];
}

// ---------------------------------------------------------------------------
// Kernel 2 (MFMA): dual QKV GEMM + sigmoid-alpha blend -> (B,N,H,P,F)
// 64x64 output tile, K=128.  4 waves of 32x32 (2x2 fragments).
// ---------------------------------------------------------------------------
__global__ __launch_bounds__(256) void qkv_mfma(
    const float* __restrict__ xc_g, const float* __restrict__ xp_g,
    const float* __restrict__ Wc, const float* __restrict__ bc,
    const float* __restrict__ Wp, const float* __restrict__ bp,
    const float* __restrict__ alpha,   // (3,1024) slice for this layer
    float* __restrict__ Q, float* __restrict__ Kout, float* __restrict__ V)
{
    __shared__ __align__(16) unsigned short xcs[64 * 128];
    __shared__ __align__(16) unsigned short xps[64 * 128];
    __shared__ __align__(16) unsigned short wcs[64 * 128];
    __shared__ __align__(16) unsigned short wps[64 * 128];
    int t = threadIdx.x;
    int BR = blockIdx.x * 64, BC = blockIdx.y * 64;

#pragma unroll
    for (int i = 0; i < 4; ++i) {
        int c = t + i * 256;            // chunk id [0,1024): 64 rows x 16 chunks
        int row = c >> 4, k0 = (c & 15) << 3;
        int di = swz(row, k0);
        cvt_store8(&xcs[di], xc_g + (size_t)(BR + row) * 128 + k0);
        cvt_store8(&xps[di], xp_g + (size_t)(BR + row) * 128 + k0);
        cvt_store8(&wcs[di], Wc + (size_t)(BC + row) * 128 + k0);
        cvt_store8(&wps[di], Wp + (size_t)(BC + row) * 128 + k0);
    }
    __syncthreads();

    int lane = t & 63, w = t >> 6;
    int wr = (w >> 1) * 32, wcol = (w & 1) * 32;
    int fr = lane & 15, fk = (lane >> 4) << 3;

    f32x4 accC[2][2] = {}, accP[2][2] = {};
#pragma unroll
    for (int kk = 0; kk < 4; ++kk) {
        int k0 = kk * 32 + fk;
        bf16x8 aC[2], aP[2], bC[2], bP[2];
#pragma unroll
        for (int m = 0; m < 2; ++m) {
            aC[m] = ld_frag(xcs, wr + m * 16 + fr, k0);
            aP[m] = ld_frag(xps, wr + m * 16 + fr, k0);
        }
#pragma unroll
        for (int n = 0; n < 2; ++n) {
            bC[n] = ld_frag(wcs, wcol + n * 16 + fr, k0);
            bP[n] = ld_frag(wps, wcol + n * 16 + fr, k0);
        }
#pragma unroll
        for (int m = 0; m < 2; ++m)
#pragma unroll
            for (int n = 0; n < 2; ++n) {
                accC[m][n] = __builtin_amdgcn_mfma_f32_16x16x32_bf16(aC[m], bC[n], accC[m][n], 0, 0, 0);
                accP[m][n] = __builtin_amdgcn_mfma_f32_16x16x32_bf16(aP[m], bP[n], accP[m][n], 0, 0, 0);
            }
    }

    // epilogue: bias + sigmoid-alpha blend, scatter to (BN,H,P,F)
#pragma unroll
    for (int n = 0; n < 2; ++n) {
        int col = BC + wcol + n * 16 + fr;      // [0,3072)
        int qkv = col >> 10, hf = col & 1023;
        int h = hf >> 7, f = hf & 127;
        float a = 1.0f / (1.0f + expf(-alpha[qkv * 1024 + hf]));
        float bcv = bc[col], bpv = bp[col];
        float* out = (qkv == 0) ? Q : ((qkv == 1) ? Kout : V);
#pragma unroll
        for (int m = 0; m < 2; ++m) {
            int rbase = BR + wr + m * 16 + ((lane >> 4) << 2);
#pragma unroll
            for (int r = 0; r < 4; ++r) {
                int row = rbase + r;            // = bn*64 + p
                int bn = row >> 6, p = row & 63;
                float val = a * (accC[m][n][r] + bcv) + (1.0f - a) * (accP[m][n][r] + bpv);
                out[(size_t)((bn * 8 + h) * 64 + p) * 128 + f] = val;
            }
        }
    }
}

// ---------------------------------------------------------------------------
// Kernel 3: attention per (b,n,h): softmax(QK^T * scale) @ V, then LN(bn1),
// written directly in (B,N,P,H*F) transposed layout.
// ---------------------------------------------------------------------------
__global__ __launch_bounds__(256) void attn_ln(
    const float* __restrict__ Q, const float* __restrict__ K,
    const float* __restrict__ V,
    const float* __restrict__ bn1s, const float* __restrict__ bn1b,
    float* __restrict__ At)
{
    int g = blockIdx.x;             // bn*8 + h
    int bn = g >> 3, h = g & 7;
    const float* Qg = Q + (size_t)g * 8192;
    const float* Kg = K + (size_t)g * 8192;
    const float* Vg = V + (size_t)g * 8192;
    __shared__ __align__(16) float Qs[64][132];
    __shared__ __align__(16) float Ks[64][132];
    __shared__ __align__(16) float Vs[64][132];
    __shared__ float Ss[64][68];
    int t = threadIdx.x;
#pragma unroll
    for (int i = 0; i < 8; ++i) {
        int lin = t + i * 256;      // [0,2048) float4s
        int r = lin >> 5, k4 = lin & 31;
        *((float4*)&Qs[r][k4 * 4]) = ((const float4*)Qg)[lin];
        *((float4*)&Ks[r][k4 * 4]) = ((const float4*)Kg)[lin];
        *((float4*)&Vs[r][k4 * 4]) = ((const float4*)Vg)[lin];
    }
    __syncthreads();

    int p = t >> 2, qo = t & 3;
    const float scale = 0.08838834764831845f;   // 128^-0.5
    float sv[16];
#pragma unroll
    for (int j = 0; j < 16; ++j) {
        int q = qo + 4 * j;
        float acc = 0.0f;
#pragma unroll 4
        for (int k = 0; k < 128; ++k) acc = fmaf(Qs[p][k], Ks[q][k], acc);
        sv[j] = acc * scale;
    }
    float mx = sv[0];
#pragma unroll
    for (int j = 1; j < 16; ++j) mx = fmaxf(mx, sv[j]);
    mx = fmaxf(mx, __shfl_xor(mx, 1, 4));
    mx = fmaxf(mx, __shfl_xor(mx, 2, 4));
    float sum = 0.0f;
#pragma unroll
    for (int j = 0; j < 16; ++j) { sv[j] = expf(sv[j] - mx); sum += sv[j]; }
    sum += __shfl_xor(sum, 1, 4);
    sum += __shfl_xor(sum, 2, 4);
    float inv = 1.0f / sum;
#pragma unroll
    for (int j = 0; j < 16; ++j) Ss[p][qo + 4 * j] = sv[j] * inv;
    __syncthreads();

    float av[32];
#pragma unroll
    for (int i = 0; i < 32; ++i) {
        int f = qo + 4 * i;
        float acc = 0.0f;
#pragma unroll 4
        for (int q = 0; q < 64; ++q) acc = fmaf(Ss[p][q], Vs[q][f], acc);
        av[i] = acc;
    }
    float s1 = 0.0f;
#pragma unroll
    for (int i = 0; i < 32; ++i) s1 += av[i];
    s1 += __shfl_xor(s1, 1, 4);
    s1 += __shfl_xor(s1, 2, 4);
    float mean = s1 * (1.0f / 128.0f);
    float s2 = 0.0f;
#pragma unroll
    for (int i = 0; i < 32; ++i) { float d = av[i] - mean; s2 += d * d; }
    s2 += __shfl_xor(s2, 1, 4);
    s2 += __shfl_xor(s2, 2, 4);
    float rs = rsqrtf(s2 * (1.0f / 128.0f) + EPS);

    float* orow = At + (size_t)(bn * 64 + p) * 1024 + h * 128;
#pragma unroll
    for (int i = 0; i < 32; ++i) {
        int f = qo + 4 * i;
        orow[f] = (av[i] - mean) * rs * bn1s[f] + bn1b[f];
    }
}

// ---------------------------------------------------------------------------
// Kernel 4 (MFMA): proj GEMM (8192x128, K=1024) + bn2 LN + gelu(cur) residual
// + ln_o LN -> O_hat.   64 rows x 128 cols per block; 4 waves of 32x64.
// ---------------------------------------------------------------------------
__global__ __launch_bounds__(256) void proj_mfma(
    const float* __restrict__ At_g, const float* __restrict__ W,
    const float* __restrict__ bias,
    const float* __restrict__ bn2s, const float* __restrict__ bn2b,
    const float* __restrict__ lnos, const float* __restrict__ lnob,
    const float* __restrict__ cur, float* __restrict__ Ohat)
{
    __shared__ __align__(16) char lds[64 * 128 * 2 + 128 * 128 * 2];   // 48KB
    unsigned short* ats = (unsigned short*)lds;                 // [64][128] bf16
    unsigned short* wts = (unsigned short*)(lds + 64 * 128 * 2); // [128][128] bf16
    float* outs = (float*)lds;                                  // reused: [64][132] f32

    int t = threadIdx.x;
    int R = blockIdx.x * 64;
    int lane = t & 63, w = t >> 6;
    int wr = (w >> 1) * 32, wcol = (w & 1) * 64;
    int fr = lane & 15, fk = (lane >> 4) << 3;

    f32x4 acc[2][4] = {};
    for (int kc = 0; kc < 8; ++kc) {
#pragma unroll
        for (int i = 0; i < 4; ++i) {
            int c = t + i * 256;        // [0,1024): At 64 rows x 16 chunks
            int row = c >> 4, k0 = (c & 15) << 3;
            cvt_store8(&ats[swz(row, k0)],
                       At_g + (size_t)(R + row) * 1024 + kc * 128 + k0);
        }
#pragma unroll
        for (int i = 0; i < 8; ++i) {
            int c = t + i * 256;        // [0,2048): W 128 rows x 16 chunks
            int row = c >> 4, k0 = (c & 15) << 3;
            cvt_store8(&wts[swz(row, k0)],
                       W + (size_t)row * 1024 + kc * 128 + k0);
        }
        __syncthreads();
#pragma unroll
        for (int kk = 0; kk < 4; ++kk) {
            int k0 = kk * 32 + fk;
            bf16x8 a[2], b[4];
#pragma unroll
            for (int m = 0; m < 2; ++m) a[m] = ld_frag(ats, wr + m * 16 + fr, k0);
#pragma unroll
            for (int n = 0; n < 4; ++n) b[n] = ld_frag(wts, wcol + n * 16 + fr, k0);
#pragma unroll
            for (int m = 0; m < 2; ++m)
#pragma unroll
                for (int n = 0; n < 4; ++n)
                    acc[m][n] = __builtin_amdgcn_mfma_f32_16x16x32_bf16(a[m], b[n], acc[m][n], 0, 0, 0);
        }
        __syncthreads();
    }

    // dump acc(+bias) to LDS f32 (aliases staging buffers — all reads done)
#pragma unroll
    for (int n = 0; n < 4; ++n) {
        int col = wcol + n * 16 + fr;
        float bv = bias[col];
#pragma unroll
        for (int m = 0; m < 2; ++m) {
            int rl = wr + m * 16 + ((lane >> 4) << 2);
#pragma unroll
            for (int r = 0; r < 4; ++r)
                outs[(rl + r) * 132 + col] = acc[m][n][r] + bv;
        }
    }
    __syncthreads();

    // LN chain: bn2 -> +gelu(cur) -> residual -> ln_o.  4 lanes per row.
    int row = t >> 2, q = t & 3;
    float vals[32];
    float s = 0.0f;
#pragma unroll
    for (int i = 0; i < 32; ++i) { vals[i] = outs[row * 132 + q + 4 * i]; s += vals[i]; }
    s += __shfl_xor(s, 1, 4);
    s += __shfl_xor(s, 2, 4);
    float mean = s * (1.0f / 128.0f);
    float sq = 0.0f;
#pragma unroll
    for (int i = 0; i < 32; ++i) { float d = vals[i] - mean; sq += d * d; }
    sq += __shfl_xor(sq, 1, 4);
    sq += __shfl_xor(sq, 2, 4);
    float rs = rsqrtf(sq * (1.0f / 128.0f) + EPS);

    float opre[32];
    float s2 = 0.0f;
#pragma unroll
    for (int i = 0; i < 32; ++i) {
        int c = q + 4 * i;
        float ynorm = (vals[i] - mean) * rs * bn2s[c] + bn2b[c];
        float cv = cur[(size_t)(R + row) * 128 + c];
        opre[i] = cv + (ynorm + gelu_f(cv));
        s2 += opre[i];
    }
    s2 += __shfl_xor(s2, 1, 4);
    s2 += __shfl_xor(s2, 2, 4);
    float mean2 = s2 * (1.0f / 128.0f);
    float sq2 = 0.0f;
#pragma unroll
    for (int i = 0; i < 32; ++i) { float d = opre[i] - mean2; sq2 += d * d; }
    sq2 += __shfl_xor(sq2, 1, 4);
    sq2 += __shfl_xor(sq2, 2, 4);
    float rs2 = rsqrtf(sq2 * (1.0f / 128.0f) + EPS);
#pragma unroll
    for (int i = 0; i < 32; ++i) {
        int c = q + 4 * i;
        Ohat[(size_t)(R + row) * 128 + c] = (opre[i] - mean2) * rs2 * lnos[c] + lnob[c];
    }
}

// ---------------------------------------------------------------------------
// Kernel 5: cur = x @ ffn_w^T + ffn_b + gelu(x)
// ---------------------------------------------------------------------------
__global__ __launch_bounds__(128) void ffn_gelu(
    const float* __restrict__ x, const float* __restrict__ W,
    const float* __restrict__ bias, float* __restrict__ y)
{
    int row = blockIdx.x;
    int c = threadIdx.x;
    __shared__ __align__(16) float xs[128];
    float xv = x[(size_t)row * 128 + c];
    xs[c] = xv;
    __syncthreads();
    float acc = bias[c];
    const float4* w4 = (const float4*)(W + (size_t)c * 128);
    const float4* x4 = (const float4*)xs;
#pragma unroll
    for (int k = 0; k < 32; ++k) {
        float4 wv = w4[k]; float4 xq = x4[k];
        acc = fmaf(wv.x, xq.x, acc); acc = fmaf(wv.y, xq.y, acc);
        acc = fmaf(wv.z, xq.z, acc); acc = fmaf(wv.w, xq.w, acc);
    }
    y[(size_t)row * 128 + c] = acc + gelu_f(xv);
}

// ---------------------------------------------------------------------------
extern "C" void kernel_launch(void* const* d_in, const int* in_sizes, int n_in,
                              void* d_out, int out_size, void* d_ws, size_t ws_size,
                              hipStream_t stream)
{
    const float* seq       = (const float*)d_in[0];
    const float* Hpre      = (const float*)d_in[1];
    const float* pro1_w    = (const float*)d_in[2];
    const float* pro1_b    = (const float*)d_in[3];
    const float* pro2_w    = (const float*)d_in[4];
    const float* pro2_b    = (const float*)d_in[5];
    const float* ln_cur_s  = (const float*)d_in[6];
    const float* ln_cur_b  = (const float*)d_in[7];
    const float* ln_pre_s  = (const float*)d_in[8];
    const float* ln_pre_b  = (const float*)d_in[9];
    const float* cur_qkv_w = (const float*)d_in[10];
    const float* cur_qkv_b = (const float*)d_in[11];
    const float* pre_qkv_w = (const float*)d_in[12];
    const float* pre_qkv_b = (const float*)d_in[13];
    const float* alpha     = (const float*)d_in[14];
    const float* proj_w    = (const float*)d_in[15];
    const float* proj_b    = (const float*)d_in[16];
    const float* bn1_s     = (const float*)d_in[17];
    const float* bn1_b     = (const float*)d_in[18];
    const float* bn2_s     = (const float*)d_in[19];
    const float* bn2_b     = (const float*)d_in[20];
    const float* ln_o_s    = (const float*)d_in[21];
    const float* ln_o_b    = (const float*)d_in[22];
    const float* ffn_w     = (const float*)d_in[23];
    const float* ffn_b     = (const float*)d_in[24];

    float* ws = (float*)d_ws;
    const size_t MF  = (size_t)8192 * 128;    // 1,048,576
    const size_t MHF = (size_t)8192 * 1024;   // 8,388,608
    float* pre  = ws;
    float* cur  = ws + MF;
    float* Ohat = ws + 2 * MF;
    float* Atb  = ws + 3 * MF;
    float* Qb   = ws + 3 * MF + MHF;
    float* Kb   = Qb + MHF;
    float* Vb   = Kb + MHF;

    for (int l = 0; l < 4; ++l) {
        if (l == 0) {
            lin128_ln<<<8192, 128, 0, stream>>>(seq, pro1_w, pro1_b,
                                                ln_cur_s, ln_cur_b, cur);
        }
        lin128_ln<<<8192, 128, 0, stream>>>(Hpre + (size_t)l * MF,
                                            pro2_w + (size_t)l * 16384,
                                            pro2_b + l * 128,
                                            ln_pre_s + l * 128, ln_pre_b + l * 128, pre);
        qkv_mfma<<<dim3(128, 48), 256, 0, stream>>>(
            cur, pre,
            cur_qkv_w + (size_t)l * 3072 * 128, cur_qkv_b + l * 3072,
            pre_qkv_w + (size_t)l * 3072 * 128, pre_qkv_b + l * 3072,
            alpha + l * 3 * 1024, Qb, Kb, Vb);
        attn_ln<<<1024, 256, 0, stream>>>(Qb, Kb, Vb,
                                          bn1_s + l * 128, bn1_b + l * 128, Atb);
        proj_mfma<<<128, 256, 0, stream>>>(Atb,
                                           proj_w + (size_t)l * 128 * 1024,
                                           proj_b + l * 128,
                                           bn2_s + l * 128, bn2_b + l * 128,
                                           ln_o_s + l * 128, ln_o_b + l * 128,
                                           cur, Ohat);
        float* outp = (l == 3) ? (float*)d_out : cur;
        ffn_gelu<<<8192, 128, 0, stream>>>(Ohat,
                                           ffn_w + (size_t)l * 16384,
                                           ffn_b + l * 128, outp);
    }
}

// Round 3
// 528.966 us; speedup vs baseline: 6.0300x; 3.7742x over previous
//
#include <hip/hip_runtime.h>
#include <math.h>

#define EPS 1e-5f

// L=4, B=16, N=8, P=64, D=128, F=128, H=8
// M = B*N*P = 8192 rows, HF = 1024, QKV width = 3072

typedef __bf16 bf16x8 __attribute__((ext_vector_type(8)));
typedef float f32x4 __attribute__((ext_vector_type(4)));

__device__ __forceinline__ float gelu_f(float x) {
    return 0.5f * x * (1.0f + erff(x * 0.7071067811865476f));
}

// convert 8 consecutive floats -> 8 bf16, store 16B to (swizzled) LDS slot
__device__ __forceinline__ void cvt_store8(void* dst, const float* __restrict__ src) {
    float4 a = ((const float4*)src)[0];
    float4 b = ((const float4*)src)[1];
    bf16x8 v;
    v[0] = (__bf16)a.x; v[1] = (__bf16)a.y; v[2] = (__bf16)a.z; v[3] = (__bf16)a.w;
    v[4] = (__bf16)b.x; v[5] = (__bf16)b.y; v[6] = (__bf16)b.z; v[7] = (__bf16)b.w;
    *(bf16x8*)dst = v;
}

// 128-wide bf16 tile, XOR swizzle: elem = row*128 + (k ^ ((row&7)<<3))
__device__ __forceinline__ int swz(int row, int k0) {
    return row * 128 + (k0 ^ ((row & 7) << 3));
}
// 64-wide bf16 tile
__device__ __forceinline__ int swz64(int row, int k0) {
    return row * 64 + (k0 ^ ((row & 7) << 3));
}

// ---------------------------------------------------------------------------
// Kernel 1 (MFMA): y = LN(x @ W^T + b) * s + t   (x:(M,128), W:(128,128))
// 32-row tile, 256 blocks; 4 waves: wave = 16 rows x 64 cols.
// ---------------------------------------------------------------------------
__global__ __launch_bounds__(256) void lin_ln_mfma(
    const float* __restrict__ x, const float* __restrict__ W,
    const float* __restrict__ bias, const float* __restrict__ lns,
    const float* __restrict__ lnb, float* __restrict__ y)
{
    __shared__ __align__(16) char lds[40960];
    unsigned short* xs = (unsigned short*)lds;            // [32][128] bf16
    unsigned short* ws = (unsigned short*)(lds + 8192);   // [128][128] bf16
    float* outs = (float*)lds;                            // [32][132] f32 alias
    int t = threadIdx.x;
    int R = blockIdx.x * 32;
#pragma unroll
    for (int i = 0; i < 2; ++i) {
        int c = t + i * 256; int row = c >> 4, k0 = (c & 15) << 3;
        cvt_store8(&xs[swz(row, k0)], x + (size_t)(R + row) * 128 + k0);
    }
#pragma unroll
    for (int i = 0; i < 8; ++i) {
        int c = t + i * 256; int row = c >> 4, k0 = (c & 15) << 3;
        cvt_store8(&ws[swz(row, k0)], W + (size_t)row * 128 + k0);
    }
    __syncthreads();
    int lane = t & 63, w = t >> 6;
    int wr = (w >> 1) * 16, wcol = (w & 1) * 64;
    int fr = lane & 15, fk = (lane >> 4) << 3;
    f32x4 acc[4] = {};
#pragma unroll
    for (int kk = 0; kk < 4; ++kk) {
        int k0 = kk * 32 + fk;
        bf16x8 a = *(const bf16x8*)&xs[swz(wr + fr, k0)];
#pragma unroll
        for (int n = 0; n < 4; ++n) {
            bf16x8 b = *(const bf16x8*)&ws[swz(wcol + n * 16 + fr, k0)];
            acc[n] = __builtin_amdgcn_mfma_f32_16x16x32_bf16(a, b, acc[n], 0, 0, 0);
        }
    }
    __syncthreads();
#pragma unroll
    for (int n = 0; n < 4; ++n) {
        int col = wcol + n * 16 + fr;
        float bv = bias[col];
        int rl = wr + ((lane >> 4) << 2);
#pragma unroll
        for (int r = 0; r < 4; ++r) outs[(rl + r) * 132 + col] = acc[n][r] + bv;
    }
    __syncthreads();
    int row = t >> 3, oc = t & 7;
    float vals[16]; float s = 0.0f;
#pragma unroll
    for (int i = 0; i < 16; ++i) { vals[i] = outs[row * 132 + oc + 8 * i]; s += vals[i]; }
    s += __shfl_xor(s, 1, 8); s += __shfl_xor(s, 2, 8); s += __shfl_xor(s, 4, 8);
    float mean = s * (1.0f / 128.0f);
    float sq = 0.0f;
#pragma unroll
    for (int i = 0; i < 16; ++i) { float d = vals[i] - mean; sq += d * d; }
    sq += __shfl_xor(sq, 1, 8); sq += __shfl_xor(sq, 2, 8); sq += __shfl_xor(sq, 4, 8);
    float rs = rsqrtf(sq * (1.0f / 128.0f) + EPS);
#pragma unroll
    for (int i = 0; i < 16; ++i) {
        int c = oc + 8 * i;
        y[(size_t)(R + row) * 128 + c] = (vals[i] - mean) * rs * lns[c] + lnb[c];
    }
}

// ---------------------------------------------------------------------------
// Kernel 2 (MFMA): dual QKV GEMM + sigmoid-alpha blend.
// Q,K -> (BN,H,P,F); V -> transposed (BN,H,F,P) for MFMA PV consumption.
// ---------------------------------------------------------------------------
__global__ __launch_bounds__(256) void qkv_mfma(
    const float* __restrict__ xc_g, const float* __restrict__ xp_g,
    const float* __restrict__ Wc, const float* __restrict__ bc,
    const float* __restrict__ Wp, const float* __restrict__ bp,
    const float* __restrict__ alpha,   // (3,1024) slice for this layer
    float* __restrict__ Q, float* __restrict__ Kout, float* __restrict__ V)
{
    __shared__ __align__(16) unsigned short xcs[64 * 128];
    __shared__ __align__(16) unsigned short xps[64 * 128];
    __shared__ __align__(16) unsigned short wcs[64 * 128];
    __shared__ __align__(16) unsigned short wps[64 * 128];
    int t = threadIdx.x;
    int BR = blockIdx.x * 64, BC = blockIdx.y * 64;

#pragma unroll
    for (int i = 0; i < 4; ++i) {
        int c = t + i * 256;
        int row = c >> 4, k0 = (c & 15) << 3;
        int di = swz(row, k0);
        cvt_store8(&xcs[di], xc_g + (size_t)(BR + row) * 128 + k0);
        cvt_store8(&xps[di], xp_g + (size_t)(BR + row) * 128 + k0);
        cvt_store8(&wcs[di], Wc + (size_t)(BC + row) * 128 + k0);
        cvt_store8(&wps[di], Wp + (size_t)(BC + row) * 128 + k0);
    }
    __syncthreads();

    int lane = t & 63, w = t >> 6;
    int wr = (w >> 1) * 32, wcol = (w & 1) * 32;
    int fr = lane & 15, fk = (lane >> 4) << 3;

    f32x4 accC[2][2] = {}, accP[2][2] = {};
#pragma unroll
    for (int kk = 0; kk < 4; ++kk) {
        int k0 = kk * 32 + fk;
        bf16x8 aC[2], aP[2], bC[2], bP[2];
#pragma unroll
        for (int m = 0; m < 2; ++m) {
            aC[m] = *(const bf16x8*)&xcs[swz(wr + m * 16 + fr, k0)];
            aP[m] = *(const bf16x8*)&xps[swz(wr + m * 16 + fr, k0)];
        }
#pragma unroll
        for (int n = 0; n < 2; ++n) {
            bC[n] = *(const bf16x8*)&wcs[swz(wcol + n * 16 + fr, k0)];
            bP[n] = *(const bf16x8*)&wps[swz(wcol + n * 16 + fr, k0)];
        }
#pragma unroll
        for (int m = 0; m < 2; ++m)
#pragma unroll
            for (int n = 0; n < 2; ++n) {
                accC[m][n] = __builtin_amdgcn_mfma_f32_16x16x32_bf16(aC[m], bC[n], accC[m][n], 0, 0, 0);
                accP[m][n] = __builtin_amdgcn_mfma_f32_16x16x32_bf16(aP[m], bP[n], accP[m][n], 0, 0, 0);
            }
    }

#pragma unroll
    for (int n = 0; n < 2; ++n) {
        int col = BC + wcol + n * 16 + fr;      // [0,3072)
        int qkv = col >> 10, hf = col & 1023;
        int h = hf >> 7, f = hf & 127;
        float a = 1.0f / (1.0f + expf(-alpha[qkv * 1024 + hf]));
        float bcv = bc[col], bpv = bp[col];
        float* out = (qkv == 0) ? Q : ((qkv == 1) ? Kout : V);
#pragma unroll
        for (int m = 0; m < 2; ++m) {
            int rbase = BR + wr + m * 16 + ((lane >> 4) << 2);
#pragma unroll
            for (int r = 0; r < 4; ++r) {
                int row = rbase + r;            // = bn*64 + p
                int bn = row >> 6, p = row & 63;
                float val = a * (accC[m][n][r] + bcv) + (1.0f - a) * (accP[m][n][r] + bpv);
                if (qkv == 2)
                    out[(size_t)((bn * 8 + h) * 128 + f) * 64 + p] = val;   // V^T
                else
                    out[(size_t)((bn * 8 + h) * 64 + p) * 128 + f] = val;
            }
        }
    }
}

// ---------------------------------------------------------------------------
// Kernel 3 (MFMA): attention per (b,n,h) + bn1 LN, transpose-write.
// 4 waves; wave w owns S/output rows [w*16, w*16+16).
// ---------------------------------------------------------------------------
__global__ __launch_bounds__(256) void attn_mfma(
    const float* __restrict__ Q, const float* __restrict__ K,
    const float* __restrict__ Vt,
    const float* __restrict__ bn1s, const float* __restrict__ bn1b,
    float* __restrict__ At)
{
    int g = blockIdx.x;             // bn*8 + h
    int bn = g >> 3, h = g & 7;
    const float* Qg = Q + (size_t)g * 8192;
    const float* Kg = K + (size_t)g * 8192;
    const float* Vg = Vt + (size_t)g * 8192;    // [128 f][64 p]
    __shared__ __align__(16) unsigned short Ks[64 * 128];
    __shared__ __align__(16) unsigned short Vs[128 * 64];
    __shared__ __align__(16) unsigned short Ps[64 * 64];
    int t = threadIdx.x;
#pragma unroll
    for (int i = 0; i < 4; ++i) {
        int c = t + i * 256;                    // [0,1024)
        int row = c >> 4, k0 = (c & 15) << 3;
        cvt_store8(&Ks[swz(row, k0)], Kg + (size_t)row * 128 + k0);
        int rv = c >> 3, kv = (c & 7) << 3;
        cvt_store8(&Vs[swz64(rv, kv)], Vg + (size_t)rv * 64 + kv);
    }
    __syncthreads();

    int lane = t & 63, w = t >> 6;
    int w16 = w * 16;
    int fr = lane & 15, fk = (lane >> 4) << 3;

    // --- QK^T: S rows [w16, w16+16), 64 cols.  Q direct from global.
    const float* qbase = Qg + (size_t)(w16 + fr) * 128;
    f32x4 sacc[4] = {};
#pragma unroll
    for (int kk = 0; kk < 4; ++kk) {
        int k0 = kk * 32 + fk;
        float4 q1 = *(const float4*)(qbase + k0);
        float4 q2 = *(const float4*)(qbase + k0 + 4);
        bf16x8 aq;
        aq[0] = (__bf16)q1.x; aq[1] = (__bf16)q1.y; aq[2] = (__bf16)q1.z; aq[3] = (__bf16)q1.w;
        aq[4] = (__bf16)q2.x; aq[5] = (__bf16)q2.y; aq[6] = (__bf16)q2.z; aq[7] = (__bf16)q2.w;
#pragma unroll
        for (int n = 0; n < 4; ++n) {
            bf16x8 bk = *(const bf16x8*)&Ks[swz(n * 16 + fr, k0)];
            sacc[n] = __builtin_amdgcn_mfma_f32_16x16x32_bf16(aq, bk, sacc[n], 0, 0, 0);
        }
    }

    // --- softmax over cols (q).  C layout: row=(lane>>4)*4+r, col=n*16+(lane&15)
    const float scale = 0.08838834764831845f;   // 128^-0.5
#pragma unroll
    for (int r = 0; r < 4; ++r) {
        float sv[4];
#pragma unroll
        for (int n = 0; n < 4; ++n) sv[n] = sacc[n][r] * scale;
        float mx = fmaxf(fmaxf(sv[0], sv[1]), fmaxf(sv[2], sv[3]));
        mx = fmaxf(mx, __shfl_xor(mx, 1, 16));
        mx = fmaxf(mx, __shfl_xor(mx, 2, 16));
        mx = fmaxf(mx, __shfl_xor(mx, 4, 16));
        mx = fmaxf(mx, __shfl_xor(mx, 8, 16));
        float sum = 0.0f;
#pragma unroll
        for (int n = 0; n < 4; ++n) { sv[n] = expf(sv[n] - mx); sum += sv[n]; }
        sum += __shfl_xor(sum, 1, 16);
        sum += __shfl_xor(sum, 2, 16);
        sum += __shfl_xor(sum, 4, 16);
        sum += __shfl_xor(sum, 8, 16);
        float inv = 1.0f / sum;
        int p = w16 + ((lane >> 4) << 2) + r;
#pragma unroll
        for (int n = 0; n < 4; ++n) {
            int q = n * 16 + fr;
            ((__bf16*)Ps)[p * 64 + (q ^ ((p & 7) << 3))] = (__bf16)(sv[n] * inv);
        }
    }
    __syncthreads();

    // --- PV: out rows [w16, w16+16), 128 cols.  A=P from Ps, B=V^T from Vs.
    f32x4 oacc[8] = {};
#pragma unroll
    for (int kk = 0; kk < 2; ++kk) {
        int k0 = kk * 32 + fk;
        bf16x8 ap = *(const bf16x8*)&Ps[swz64(w16 + fr, k0)];
#pragma unroll
        for (int n = 0; n < 8; ++n) {
            bf16x8 bv = *(const bf16x8*)&Vs[swz64(n * 16 + fr, k0)];
            oacc[n] = __builtin_amdgcn_mfma_f32_16x16x32_bf16(ap, bv, oacc[n], 0, 0, 0);
        }
    }

    // --- bn1 LN over f (128) + transposed write to At (bn,p, h*128+f)
#pragma unroll
    for (int r = 0; r < 4; ++r) {
        int p = w16 + ((lane >> 4) << 2) + r;
        float s1 = 0.0f;
#pragma unroll
        for (int n = 0; n < 8; ++n) s1 += oacc[n][r];
        s1 += __shfl_xor(s1, 1, 16);
        s1 += __shfl_xor(s1, 2, 16);
        s1 += __shfl_xor(s1, 4, 16);
        s1 += __shfl_xor(s1, 8, 16);
        float mean = s1 * (1.0f / 128.0f);
        float s2 = 0.0f;
#pragma unroll
        for (int n = 0; n < 8; ++n) { float d = oacc[n][r] - mean; s2 += d * d; }
        s2 += __shfl_xor(s2, 1, 16);
        s2 += __shfl_xor(s2, 2, 16);
        s2 += __shfl_xor(s2, 4, 16);
        s2 += __shfl_xor(s2, 8, 16);
        float rs = rsqrtf(s2 * (1.0f / 128.0f) + EPS);
        float* orow = At + (size_t)(bn * 64 + p) * 1024 + h * 128;
#pragma unroll
        for (int n = 0; n < 8; ++n) {
            int f = n * 16 + fr;
            orow[f] = (oacc[n][r] - mean) * rs * bn1s[f] + bn1b[f];
        }
    }
}

// ---------------------------------------------------------------------------
// Kernel 4 (MFMA): proj (K=1024) + bn2 LN + gelu(cur) residual + ln_o LN
// + ffn GEMM + gelu(O_hat)  -> cur/out.  32-row tile, 256 blocks.
// ---------------------------------------------------------------------------
__global__ __launch_bounds__(256) void proj_ffn_mfma(
    const float* __restrict__ At_g, const float* __restrict__ Wp,
    const float* __restrict__ pb,
    const float* __restrict__ bn2s, const float* __restrict__ bn2b,
    const float* __restrict__ lnos, const float* __restrict__ lnob,
    const float* __restrict__ Wf, const float* __restrict__ fb,
    const float* __restrict__ cur, float* __restrict__ out)
{
    __shared__ __align__(16) char lds[40960];
    unsigned short* ats = (unsigned short*)lds;           // [32][128] bf16 (ph1: At, ph3: O_hat)
    unsigned short* wts = (unsigned short*)(lds + 8192);  // [128][128] bf16 (ph1: Wp chunk, ph3: Wf)
    float* outs = (float*)lds;                            // [32][132] f32 (ph2)
    int t = threadIdx.x;
    int R = blockIdx.x * 32;
    int lane = t & 63, w = t >> 6;
    int wr = (w >> 1) * 16, wcol = (w & 1) * 64;
    int fr = lane & 15, fk = (lane >> 4) << 3;

    // ---- phase 1: proj GEMM over 8 K-chunks
    f32x4 acc[4] = {};
    for (int kc = 0; kc < 8; ++kc) {
#pragma unroll
        for (int i = 0; i < 2; ++i) {
            int c = t + i * 256; int row = c >> 4, k0 = (c & 15) << 3;
            cvt_store8(&ats[swz(row, k0)], At_g + (size_t)(R + row) * 1024 + kc * 128 + k0);
        }
#pragma unroll
        for (int i = 0; i < 8; ++i) {
            int c = t + i * 256; int row = c >> 4, k0 = (c & 15) << 3;
            cvt_store8(&wts[swz(row, k0)], Wp + (size_t)row * 1024 + kc * 128 + k0);
        }
        __syncthreads();
#pragma unroll
        for (int kk = 0; kk < 4; ++kk) {
            int k0 = kk * 32 + fk;
            bf16x8 a = *(const bf16x8*)&ats[swz(wr + fr, k0)];
#pragma unroll
            for (int n = 0; n < 4; ++n) {
                bf16x8 b = *(const bf16x8*)&wts[swz(wcol + n * 16 + fr, k0)];
                acc[n] = __builtin_amdgcn_mfma_f32_16x16x32_bf16(a, b, acc[n], 0, 0, 0);
            }
        }
        __syncthreads();
    }

    // ---- dump acc(+bias) to f32 LDS
#pragma unroll
    for (int n = 0; n < 4; ++n) {
        int col = wcol + n * 16 + fr;
        float bv = pb[col];
        int rl = wr + ((lane >> 4) << 2);
#pragma unroll
        for (int r = 0; r < 4; ++r) outs[(rl + r) * 132 + col] = acc[n][r] + bv;
    }
    __syncthreads();

    // ---- phase 2: bn2 LN -> +gelu(cur) residual -> ln_o LN (8 lanes/row)
    int row = t >> 3, oc = t & 7;
    float vals[16]; float s = 0.0f;
#pragma unroll
    for (int i = 0; i < 16; ++i) { vals[i] = outs[row * 132 + oc + 8 * i]; s += vals[i]; }
    s += __shfl_xor(s, 1, 8); s += __shfl_xor(s, 2, 8); s += __shfl_xor(s, 4, 8);
    float mean = s * (1.0f / 128.0f);
    float sq = 0.0f;
#pragma unroll
    for (int i = 0; i < 16; ++i) { float d = vals[i] - mean; sq += d * d; }
    sq += __shfl_xor(sq, 1, 8); sq += __shfl_xor(sq, 2, 8); sq += __shfl_xor(sq, 4, 8);
    float rs = rsqrtf(sq * (1.0f / 128.0f) + EPS);

    float oh[16]; float s2 = 0.0f;
#pragma unroll
    for (int i = 0; i < 16; ++i) {
        int c = oc + 8 * i;
        float ynorm = (vals[i] - mean) * rs * bn2s[c] + bn2b[c];
        float cv = cur[(size_t)(R + row) * 128 + c];
        oh[i] = cv + (ynorm + gelu_f(cv));
        s2 += oh[i];
    }
    s2 += __shfl_xor(s2, 1, 8); s2 += __shfl_xor(s2, 2, 8); s2 += __shfl_xor(s2, 4, 8);
    float mean2 = s2 * (1.0f / 128.0f);
    float sq2 = 0.0f;
#pragma unroll
    for (int i = 0; i < 16; ++i) { float d = oh[i] - mean2; sq2 += d * d; }
    sq2 += __shfl_xor(sq2, 1, 8); sq2 += __shfl_xor(sq2, 2, 8); sq2 += __shfl_xor(sq2, 4, 8);
    float rs2 = rsqrtf(sq2 * (1.0f / 128.0f) + EPS);
#pragma unroll
    for (int i = 0; i < 16; ++i) {
        int c = oc + 8 * i;
        oh[i] = (oh[i] - mean2) * rs2 * lnos[c] + lnob[c];   // O_hat
    }
    __syncthreads();

    // ---- phase 3: stage O_hat (bf16) + Wf, ffn GEMM + gelu epilogue
#pragma unroll
    for (int i = 0; i < 16; ++i) {
        int c = oc + 8 * i;
        ((__bf16*)ats)[row * 128 + (c ^ ((row & 7) << 3))] = (__bf16)oh[i];
    }
#pragma unroll
    for (int i = 0; i < 8; ++i) {
        int c = t + i * 256; int rw = c >> 4, k0 = (c & 15) << 3;
        cvt_store8(&wts[swz(rw, k0)], Wf + (size_t)rw * 128 + k0);
    }
    __syncthreads();

    f32x4 acc2[4] = {};
#pragma unroll
    for (int kk = 0; kk < 4; ++kk) {
        int k0 = kk * 32 + fk;
        bf16x8 a = *(const bf16x8*)&ats[swz(wr + fr, k0)];
#pragma unroll
        for (int n = 0; n < 4; ++n) {
            bf16x8 b = *(const bf16x8*)&wts[swz(wcol + n * 16 + fr, k0)];
            acc2[n] = __builtin_amdgcn_mfma_f32_16x16x32_bf16(a, b, acc2[n], 0, 0, 0);
        }
    }
#pragma unroll
    for (int n = 0; n < 4; ++n) {
        int col = wcol + n * 16 + fr;
        float bv = fb[col];
#pragma unroll
        for (int r = 0; r < 4; ++r) {
            int ro = wr + ((lane >> 4) << 2) + r;
            float ov = (float)((__bf16*)ats)[ro * 128 + (col ^ ((ro & 7) << 3))];
            out[(size_t)(R + ro) * 128 + col] = acc2[n][r] + bv + gelu_f(ov);
        }
    }
}

// ---------------------------------------------------------------------------
extern "C" void kernel_launch(void* const* d_in, const int* in_sizes, int n_in,
                              void* d_out, int out_size, void* d_ws, size_t ws_size,
                              hipStream_t stream)
{
    const float* seq       = (const float*)d_in[0];
    const float* Hpre      = (const float*)d_in[1];
    const float* pro1_w    = (const float*)d_in[2];
    const float* pro1_b    = (const float*)d_in[3];
    const float* pro2_w    = (const float*)d_in[4];
    const float* pro2_b    = (const float*)d_in[5];
    const float* ln_cur_s  = (const float*)d_in[6];
    const float* ln_cur_b  = (const float*)d_in[7];
    const float* ln_pre_s  = (const float*)d_in[8];
    const float* ln_pre_b  = (const float*)d_in[9];
    const float* cur_qkv_w = (const float*)d_in[10];
    const float* cur_qkv_b = (const float*)d_in[11];
    const float* pre_qkv_w = (const float*)d_in[12];
    const float* pre_qkv_b = (const float*)d_in[13];
    const float* alpha     = (const float*)d_in[14];
    const float* proj_w    = (const float*)d_in[15];
    const float* proj_b    = (const float*)d_in[16];
    const float* bn1_s     = (const float*)d_in[17];
    const float* bn1_b     = (const float*)d_in[18];
    const float* bn2_s     = (const float*)d_in[19];
    const float* bn2_b     = (const float*)d_in[20];
    const float* ln_o_s    = (const float*)d_in[21];
    const float* ln_o_b    = (const float*)d_in[22];
    const float* ffn_w     = (const float*)d_in[23];
    const float* ffn_b     = (const float*)d_in[24];

    float* ws = (float*)d_ws;
    const size_t MF  = (size_t)8192 * 128;    // 1,048,576
    const size_t MHF = (size_t)8192 * 1024;   // 8,388,608
    float* pre  = ws;
    float* cur  = ws + MF;
    float* Atb  = ws + 3 * MF;
    float* Qb   = ws + 3 * MF + MHF;
    float* Kb   = Qb + MHF;
    float* Vb   = Kb + MHF;          // stored transposed (BN,H,F,P)

    for (int l = 0; l < 4; ++l) {
        if (l == 0) {
            lin_ln_mfma<<<256, 256, 0, stream>>>(seq, pro1_w, pro1_b,
                                                 ln_cur_s, ln_cur_b, cur);
        }
        lin_ln_mfma<<<256, 256, 0, stream>>>(Hpre + (size_t)l * MF,
                                             pro2_w + (size_t)l * 16384,
                                             pro2_b + l * 128,
                                             ln_pre_s + l * 128, ln_pre_b + l * 128, pre);
        qkv_mfma<<<dim3(128, 48), 256, 0, stream>>>(
            cur, pre,
            cur_qkv_w + (size_t)l * 3072 * 128, cur_qkv_b + l * 3072,
            pre_qkv_w + (size_t)l * 3072 * 128, pre_qkv_b + l * 3072,
            alpha + l * 3 * 1024, Qb, Kb, Vb);
        attn_mfma<<<1024, 256, 0, stream>>>(Qb, Kb, Vb,
                                            bn1_s + l * 128, bn1_b + l * 128, Atb);
        float* outp = (l == 3) ? (float*)d_out : cur;
        proj_ffn_mfma<<<256, 256, 0, stream>>>(Atb,
                                               proj_w + (size_t)l * 128 * 1024,
                                               proj_b + l * 128,
                                               bn2_s + l * 128, bn2_b + l * 128,
                                               ln_o_s + l * 128, ln_o_b + l * 128,
                                               ffn_w + (size_t)l * 16384,
                                               ffn_b + l * 128,
                                               cur, outp);
    }
}

// Round 4
// 360.325 us; speedup vs baseline: 8.8521x; 1.4680x over previous
//
#include <hip/hip_runtime.h>
#include <math.h>

#define EPS 1e-5f

// L=4, B=16, N=8, P=64, D=128, F=128, H=8
// M = B*N*P = 8192 rows, HF = 1024, QKV width = 3072

typedef __bf16 bf16x8 __attribute__((ext_vector_type(8)));
typedef float f32x4 __attribute__((ext_vector_type(4)));

__device__ __forceinline__ float gelu_f(float x) {
    return 0.5f * x * (1.0f + erff(x * 0.7071067811865476f));
}

// convert 8 consecutive floats -> 8 bf16, store 16B to (swizzled) LDS slot
__device__ __forceinline__ void cvt_store8(void* dst, const float* __restrict__ src) {
    float4 a = ((const float4*)src)[0];
    float4 b = ((const float4*)src)[1];
    bf16x8 v;
    v[0] = (__bf16)a.x; v[1] = (__bf16)a.y; v[2] = (__bf16)a.z; v[3] = (__bf16)a.w;
    v[4] = (__bf16)b.x; v[5] = (__bf16)b.y; v[6] = (__bf16)b.z; v[7] = (__bf16)b.w;
    *(bf16x8*)dst = v;
}

// 128-wide bf16 tile, XOR swizzle: elem = row*128 + (k ^ ((row&7)<<3))
__device__ __forceinline__ int swz(int row, int k0) {
    return row * 128 + (k0 ^ ((row & 7) << 3));
}
// 64-wide bf16 tile
__device__ __forceinline__ int swz64(int row, int k0) {
    return row * 64 + (k0 ^ ((row & 7) << 3));
}

// ---------------------------------------------------------------------------
// Precompute A: blend-folded QKV weight  W'[l] = [a*Wc | (1-a)*Wp]  (bf16)
// and bias b' = a*bc + (1-a)*bp (f32).   4*3072*32 groups of 8 cols.
// ---------------------------------------------------------------------------
__global__ __launch_bounds__(256) void build_wq(
    const float* __restrict__ Wc, const float* __restrict__ bc,
    const float* __restrict__ Wp, const float* __restrict__ bp,
    const float* __restrict__ alpha,
    __bf16* __restrict__ Wq, float* __restrict__ bq)
{
    int idx = blockIdx.x * 256 + threadIdx.x;      // [0, 393216)
    int l = idx / 98304, rem = idx - l * 98304;    // 98304 = 3072*32
    int row = rem >> 5, g = rem & 31, k0 = g << 3;
    float a = 1.0f / (1.0f + expf(-alpha[l * 3072 + row]));
    __bf16* dst = Wq + ((size_t)l * 3072 + row) * 256 + k0;
    if (k0 < 128) {
        const float* s = Wc + ((size_t)l * 3072 + row) * 128 + k0;
#pragma unroll
        for (int j = 0; j < 8; ++j) dst[j] = (__bf16)(a * s[j]);
    } else {
        const float* s = Wp + ((size_t)l * 3072 + row) * 128 + (k0 - 128);
#pragma unroll
        for (int j = 0; j < 8; ++j) dst[j] = (__bf16)((1.0f - a) * s[j]);
    }
    if (g == 0)
        bq[l * 3072 + row] = a * bc[l * 3072 + row] + (1.0f - a) * bp[l * 3072 + row];
}

// ---------------------------------------------------------------------------
// Precompute B: plain f32 -> bf16 tensor conversion
// ---------------------------------------------------------------------------
__global__ __launch_bounds__(256) void cvt_bf16(
    const float* __restrict__ src, __bf16* __restrict__ dst, int n)
{
    int i = (blockIdx.x * 256 + threadIdx.x) * 4;
    if (i < n) {
        float4 v = *(const float4*)(src + i);
        dst[i] = (__bf16)v.x; dst[i + 1] = (__bf16)v.y;
        dst[i + 2] = (__bf16)v.z; dst[i + 3] = (__bf16)v.w;
    }
}

// ---------------------------------------------------------------------------
// Kernel 1 (MFMA): y = LN(x @ W^T + b)*s + t.  64-row tile, grid 128.
// Writes optional f32 y and a bf16 copy into X (stride 256, cur/pre half).
// ---------------------------------------------------------------------------
__global__ __launch_bounds__(256) void lin_ln_mfma(
    const float* __restrict__ x, const __bf16* __restrict__ Wbf,
    const float* __restrict__ bias, const float* __restrict__ lns,
    const float* __restrict__ lnb,
    float* __restrict__ yf, __bf16* __restrict__ Xout)
{
    __shared__ __align__(16) char lds[49152];
    unsigned short* xs = (unsigned short*)lds;            // [64][128] bf16
    unsigned short* ws = (unsigned short*)(lds + 16384);  // [128][128] bf16
    float* outs = (float*)lds;                            // [64][132] f32 alias
    int t = threadIdx.x;
    int R = blockIdx.x * 64;
#pragma unroll
    for (int i = 0; i < 4; ++i) {
        int c = t + i * 256; int row = c >> 4, k0 = (c & 15) << 3;
        cvt_store8(&xs[swz(row, k0)], x + (size_t)(R + row) * 128 + k0);
    }
#pragma unroll
    for (int i = 0; i < 8; ++i) {
        int c = t + i * 256; int row = c >> 4, k0 = (c & 15) << 3;
        *(bf16x8*)&ws[swz(row, k0)] = *(const bf16x8*)(Wbf + (size_t)row * 128 + k0);
    }
    __syncthreads();
    int lane = t & 63, w = t >> 6;
    int wr = w * 16;
    int fr = lane & 15, fk = (lane >> 4) << 3;
    f32x4 acc[8] = {};
#pragma unroll
    for (int kk = 0; kk < 4; ++kk) {
        int k0 = kk * 32 + fk;
        bf16x8 a = *(const bf16x8*)&xs[swz(wr + fr, k0)];
#pragma unroll
        for (int n = 0; n < 8; ++n) {
            bf16x8 b = *(const bf16x8*)&ws[swz(n * 16 + fr, k0)];
            acc[n] = __builtin_amdgcn_mfma_f32_16x16x32_bf16(a, b, acc[n], 0, 0, 0);
        }
    }
    __syncthreads();
#pragma unroll
    for (int n = 0; n < 8; ++n) {
        int col = n * 16 + fr;
        float bv = bias[col];
        int rl = wr + ((lane >> 4) << 2);
#pragma unroll
        for (int r = 0; r < 4; ++r) outs[(rl + r) * 132 + col] = acc[n][r] + bv;
    }
    __syncthreads();
    int row = t >> 2, oc = t & 3;
    float vals[32]; float s = 0.0f;
#pragma unroll
    for (int i = 0; i < 32; ++i) { vals[i] = outs[row * 132 + oc + 4 * i]; s += vals[i]; }
    s += __shfl_xor(s, 1, 4); s += __shfl_xor(s, 2, 4);
    float mean = s * (1.0f / 128.0f);
    float sq = 0.0f;
#pragma unroll
    for (int i = 0; i < 32; ++i) { float d = vals[i] - mean; sq += d * d; }
    sq += __shfl_xor(sq, 1, 4); sq += __shfl_xor(sq, 2, 4);
    float rs = rsqrtf(sq * (1.0f / 128.0f) + EPS);
#pragma unroll
    for (int i = 0; i < 32; ++i) {
        int c = oc + 4 * i;
        float yv = (vals[i] - mean) * rs * lns[c] + lnb[c];
        if (yf) yf[(size_t)(R + row) * 128 + c] = yv;
        Xout[(size_t)(R + row) * 256 + c] = (__bf16)yv;
    }
}

// ---------------------------------------------------------------------------
// Kernel 2 (MFMA): single folded QKV GEMM: X(8192x256) @ Wq(3072x256)^T + bq.
// 128x64 tile, grid (64,48).  Q,K -> (BN,H,P,F) bf16; V -> (BN,H,F,P) bf16.
// ---------------------------------------------------------------------------
__global__ __launch_bounds__(256) void qkv_mfma(
    const __bf16* __restrict__ X, const __bf16* __restrict__ Wq,
    const float* __restrict__ bq,
    __bf16* __restrict__ Q, __bf16* __restrict__ Kout, __bf16* __restrict__ Vt)
{
    __shared__ __align__(16) unsigned short Xs[128 * 128];  // 32KB
    __shared__ __align__(16) unsigned short Ws[64 * 128];   // 16KB
    int t = threadIdx.x, lane = t & 63, w = t >> 6;
    int BR = blockIdx.x * 128, BC = blockIdx.y * 64;
    int wr = (w >> 1) * 64, wc = (w & 1) * 32;
    int fr = lane & 15, fk = (lane >> 4) << 3;

    f32x4 acc[4][2] = {};
    for (int kc = 0; kc < 2; ++kc) {
#pragma unroll
        for (int i = 0; i < 8; ++i) {
            int c = t + i * 256; int row = c >> 4, k0 = (c & 15) << 3;
            *(bf16x8*)&Xs[swz(row, k0)] =
                *(const bf16x8*)(X + (size_t)(BR + row) * 256 + kc * 128 + k0);
        }
#pragma unroll
        for (int i = 0; i < 4; ++i) {
            int c = t + i * 256; int row = c >> 4, k0 = (c & 15) << 3;
            *(bf16x8*)&Ws[swz(row, k0)] =
                *(const bf16x8*)(Wq + (size_t)(BC + row) * 256 + kc * 128 + k0);
        }
        __syncthreads();
#pragma unroll
        for (int kk = 0; kk < 4; ++kk) {
            int k0 = kk * 32 + fk;
            bf16x8 a[4], b[2];
#pragma unroll
            for (int m = 0; m < 4; ++m) a[m] = *(const bf16x8*)&Xs[swz(wr + m * 16 + fr, k0)];
#pragma unroll
            for (int n = 0; n < 2; ++n) b[n] = *(const bf16x8*)&Ws[swz(wc + n * 16 + fr, k0)];
#pragma unroll
            for (int m = 0; m < 4; ++m)
#pragma unroll
                for (int n = 0; n < 2; ++n)
                    acc[m][n] = __builtin_amdgcn_mfma_f32_16x16x32_bf16(a[m], b[n], acc[m][n], 0, 0, 0);
        }
        __syncthreads();
    }

#pragma unroll
    for (int n = 0; n < 2; ++n) {
        int col = BC + wc + n * 16 + fr;        // [0,3072)
        int qkv = col >> 10, hf = col & 1023;
        int h = hf >> 7, f = hf & 127;
        float bv = bq[col];
#pragma unroll
        for (int m = 0; m < 4; ++m) {
            int rb = BR + wr + m * 16 + ((lane >> 4) << 2);
#pragma unroll
            for (int r = 0; r < 4; ++r) {
                int row = rb + r;               // = bn*64 + p
                int bn = row >> 6, p = row & 63;
                float val = acc[m][n][r] + bv;
                if (qkv == 2)
                    Vt[(size_t)((bn * 8 + h) * 128 + f) * 64 + p] = (__bf16)val;
                else if (qkv == 1)
                    Kout[(size_t)((bn * 8 + h) * 64 + p) * 128 + f] = (__bf16)val;
                else
                    Q[(size_t)((bn * 8 + h) * 64 + p) * 128 + f] = (__bf16)val;
            }
        }
    }
}

// ---------------------------------------------------------------------------
// Kernel 3 (MFMA): attention per (b,n,h) + bn1 LN -> At bf16 (B,N,P,H*F).
// ---------------------------------------------------------------------------
__global__ __launch_bounds__(256) void attn_mfma(
    const __bf16* __restrict__ Q, const __bf16* __restrict__ K,
    const __bf16* __restrict__ Vt,
    const float* __restrict__ bn1s, const float* __restrict__ bn1b,
    __bf16* __restrict__ At)
{
    int g = blockIdx.x;             // bn*8 + h
    int bn = g >> 3, h = g & 7;
    const __bf16* Qg = Q + (size_t)g * 8192;
    const __bf16* Kg = K + (size_t)g * 8192;
    const __bf16* Vg = Vt + (size_t)g * 8192;   // [128 f][64 p]
    __shared__ __align__(16) unsigned short Ks[64 * 128];
    __shared__ __align__(16) unsigned short Vs[128 * 64];
    __shared__ __align__(16) unsigned short Ps[64 * 64];
    int t = threadIdx.x;
#pragma unroll
    for (int i = 0; i < 4; ++i) {
        int c = t + i * 256;                    // [0,1024)
        int row = c >> 4, k0 = (c & 15) << 3;
        *(bf16x8*)&Ks[swz(row, k0)] = *(const bf16x8*)(Kg + (size_t)row * 128 + k0);
        int rv = c >> 3, kv = (c & 7) << 3;
        *(bf16x8*)&Vs[swz64(rv, kv)] = *(const bf16x8*)(Vg + (size_t)rv * 64 + kv);
    }
    __syncthreads();

    int lane = t & 63, w = t >> 6;
    int w16 = w * 16;
    int fr = lane & 15, fk = (lane >> 4) << 3;

    // --- QK^T: Q fragments direct from global (bf16)
    const __bf16* qbase = Qg + (size_t)(w16 + fr) * 128;
    f32x4 sacc[4] = {};
#pragma unroll
    for (int kk = 0; kk < 4; ++kk) {
        int k0 = kk * 32 + fk;
        bf16x8 aq = *(const bf16x8*)(qbase + k0);
#pragma unroll
        for (int n = 0; n < 4; ++n) {
            bf16x8 bk = *(const bf16x8*)&Ks[swz(n * 16 + fr, k0)];
            sacc[n] = __builtin_amdgcn_mfma_f32_16x16x32_bf16(aq, bk, sacc[n], 0, 0, 0);
        }
    }

    const float scale = 0.08838834764831845f;   // 128^-0.5
#pragma unroll
    for (int r = 0; r < 4; ++r) {
        float sv[4];
#pragma unroll
        for (int n = 0; n < 4; ++n) sv[n] = sacc[n][r] * scale;
        float mx = fmaxf(fmaxf(sv[0], sv[1]), fmaxf(sv[2], sv[3]));
        mx = fmaxf(mx, __shfl_xor(mx, 1, 16));
        mx = fmaxf(mx, __shfl_xor(mx, 2, 16));
        mx = fmaxf(mx, __shfl_xor(mx, 4, 16));
        mx = fmaxf(mx, __shfl_xor(mx, 8, 16));
        float sum = 0.0f;
#pragma unroll
        for (int n = 0; n < 4; ++n) { sv[n] = expf(sv[n] - mx); sum += sv[n]; }
        sum += __shfl_xor(sum, 1, 16);
        sum += __shfl_xor(sum, 2, 16);
        sum += __shfl_xor(sum, 4, 16);
        sum += __shfl_xor(sum, 8, 16);
        float inv = 1.0f / sum;
        int p = w16 + ((lane >> 4) << 2) + r;
#pragma unroll
        for (int n = 0; n < 4; ++n) {
            int q = n * 16 + fr;
            ((__bf16*)Ps)[p * 64 + (q ^ ((p & 7) << 3))] = (__bf16)(sv[n] * inv);
        }
    }
    __syncthreads();

    // --- PV
    f32x4 oacc[8] = {};
#pragma unroll
    for (int kk = 0; kk < 2; ++kk) {
        int k0 = kk * 32 + fk;
        bf16x8 ap = *(const bf16x8*)&Ps[swz64(w16 + fr, k0)];
#pragma unroll
        for (int n = 0; n < 8; ++n) {
            bf16x8 bv = *(const bf16x8*)&Vs[swz64(n * 16 + fr, k0)];
            oacc[n] = __builtin_amdgcn_mfma_f32_16x16x32_bf16(ap, bv, oacc[n], 0, 0, 0);
        }
    }

    // --- bn1 LN over f + transposed bf16 write
#pragma unroll
    for (int r = 0; r < 4; ++r) {
        int p = w16 + ((lane >> 4) << 2) + r;
        float s1 = 0.0f;
#pragma unroll
        for (int n = 0; n < 8; ++n) s1 += oacc[n][r];
        s1 += __shfl_xor(s1, 1, 16);
        s1 += __shfl_xor(s1, 2, 16);
        s1 += __shfl_xor(s1, 4, 16);
        s1 += __shfl_xor(s1, 8, 16);
        float mean = s1 * (1.0f / 128.0f);
        float s2 = 0.0f;
#pragma unroll
        for (int n = 0; n < 8; ++n) { float d = oacc[n][r] - mean; s2 += d * d; }
        s2 += __shfl_xor(s2, 1, 16);
        s2 += __shfl_xor(s2, 2, 16);
        s2 += __shfl_xor(s2, 4, 16);
        s2 += __shfl_xor(s2, 8, 16);
        float rs = rsqrtf(s2 * (1.0f / 128.0f) + EPS);
        __bf16* orow = At + (size_t)(bn * 64 + p) * 1024 + h * 128;
#pragma unroll
        for (int n = 0; n < 8; ++n) {
            int f = n * 16 + fr;
            orow[f] = (__bf16)((oacc[n][r] - mean) * rs * bn1s[f] + bn1b[f]);
        }
    }
}

// ---------------------------------------------------------------------------
// Kernel 4 (MFMA): proj (K=1024) + bn2 LN + gelu(cur) residual + ln_o LN
// + ffn GEMM + gelu(O_hat).  32-row tile, grid 256.
// ---------------------------------------------------------------------------
__global__ __launch_bounds__(256) void proj_ffn_mfma(
    const __bf16* __restrict__ At_g, const __bf16* __restrict__ Wp,
    const float* __restrict__ pb,
    const float* __restrict__ bn2s, const float* __restrict__ bn2b,
    const float* __restrict__ lnos, const float* __restrict__ lnob,
    const __bf16* __restrict__ Wf, const float* __restrict__ fb,
    const float* __restrict__ cur, float* __restrict__ out,
    __bf16* __restrict__ Xcur)
{
    __shared__ __align__(16) char lds[40960];
    unsigned short* ats = (unsigned short*)lds;           // [32][128] bf16
    unsigned short* wts = (unsigned short*)(lds + 8192);  // [128][128] bf16
    float* outs = (float*)lds;                            // [32][132] f32 alias
    int t = threadIdx.x;
    int R = blockIdx.x * 32;
    int lane = t & 63, w = t >> 6;
    int wr = (w >> 1) * 16, wcol = (w & 1) * 64;
    int fr = lane & 15, fk = (lane >> 4) << 3;

    // ---- phase 1: proj GEMM over 8 K-chunks
    f32x4 acc[4] = {};
    for (int kc = 0; kc < 8; ++kc) {
#pragma unroll
        for (int i = 0; i < 2; ++i) {
            int c = t + i * 256; int row = c >> 4, k0 = (c & 15) << 3;
            *(bf16x8*)&ats[swz(row, k0)] =
                *(const bf16x8*)(At_g + (size_t)(R + row) * 1024 + kc * 128 + k0);
        }
#pragma unroll
        for (int i = 0; i < 8; ++i) {
            int c = t + i * 256; int row = c >> 4, k0 = (c & 15) << 3;
            *(bf16x8*)&wts[swz(row, k0)] =
                *(const bf16x8*)(Wp + (size_t)row * 1024 + kc * 128 + k0);
        }
        __syncthreads();
#pragma unroll
        for (int kk = 0; kk < 4; ++kk) {
            int k0 = kk * 32 + fk;
            bf16x8 a = *(const bf16x8*)&ats[swz(wr + fr, k0)];
#pragma unroll
            for (int n = 0; n < 4; ++n) {
                bf16x8 b = *(const bf16x8*)&wts[swz(wcol + n * 16 + fr, k0)];
                acc[n] = __builtin_amdgcn_mfma_f32_16x16x32_bf16(a, b, acc[n], 0, 0, 0);
            }
        }
        __syncthreads();
    }

#pragma unroll
    for (int n = 0; n < 4; ++n) {
        int col = wcol + n * 16 + fr;
        float bv = pb[col];
        int rl = wr + ((lane >> 4) << 2);
#pragma unroll
        for (int r = 0; r < 4; ++r) outs[(rl + r) * 132 + col] = acc[n][r] + bv;
    }
    __syncthreads();

    // ---- phase 2: bn2 LN -> +gelu(cur) residual -> ln_o LN (8 lanes/row)
    int row = t >> 3, oc = t & 7;
    float vals[16]; float s = 0.0f;
#pragma unroll
    for (int i = 0; i < 16; ++i) { vals[i] = outs[row * 132 + oc + 8 * i]; s += vals[i]; }
    s += __shfl_xor(s, 1, 8); s += __shfl_xor(s, 2, 8); s += __shfl_xor(s, 4, 8);
    float mean = s * (1.0f / 128.0f);
    float sq = 0.0f;
#pragma unroll
    for (int i = 0; i < 16; ++i) { float d = vals[i] - mean; sq += d * d; }
    sq += __shfl_xor(sq, 1, 8); sq += __shfl_xor(sq, 2, 8); sq += __shfl_xor(sq, 4, 8);
    float rs = rsqrtf(sq * (1.0f / 128.0f) + EPS);

    float oh[16]; float s2 = 0.0f;
#pragma unroll
    for (int i = 0; i < 16; ++i) {
        int c = oc + 8 * i;
        float ynorm = (vals[i] - mean) * rs * bn2s[c] + bn2b[c];
        float cv = cur[(size_t)(R + row) * 128 + c];
        oh[i] = cv + (ynorm + gelu_f(cv));
        s2 += oh[i];
    }
    s2 += __shfl_xor(s2, 1, 8); s2 += __shfl_xor(s2, 2, 8); s2 += __shfl_xor(s2, 4, 8);
    float mean2 = s2 * (1.0f / 128.0f);
    float sq2 = 0.0f;
#pragma unroll
    for (int i = 0; i < 16; ++i) { float d = oh[i] - mean2; sq2 += d * d; }
    sq2 += __shfl_xor(sq2, 1, 8); sq2 += __shfl_xor(sq2, 2, 8); sq2 += __shfl_xor(sq2, 4, 8);
    float rs2 = rsqrtf(sq2 * (1.0f / 128.0f) + EPS);
#pragma unroll
    for (int i = 0; i < 16; ++i) {
        int c = oc + 8 * i;
        oh[i] = (oh[i] - mean2) * rs2 * lnos[c] + lnob[c];   // O_hat
    }
    __syncthreads();

    // ---- phase 3: stage O_hat (bf16) + Wf, ffn GEMM + gelu epilogue
#pragma unroll
    for (int i = 0; i < 16; ++i) {
        int c = oc + 8 * i;
        ((__bf16*)ats)[row * 128 + (c ^ ((row & 7) << 3))] = (__bf16)oh[i];
    }
#pragma unroll
    for (int i = 0; i < 8; ++i) {
        int c = t + i * 256; int rw = c >> 4, k0 = (c & 15) << 3;
        *(bf16x8*)&wts[swz(rw, k0)] = *(const bf16x8*)(Wf + (size_t)rw * 128 + k0);
    }
    __syncthreads();

    f32x4 acc2[4] = {};
#pragma unroll
    for (int kk = 0; kk < 4; ++kk) {
        int k0 = kk * 32 + fk;
        bf16x8 a = *(const bf16x8*)&ats[swz(wr + fr, k0)];
#pragma unroll
        for (int n = 0; n < 4; ++n) {
            bf16x8 b = *(const bf16x8*)&wts[swz(wcol + n * 16 + fr, k0)];
            acc2[n] = __builtin_amdgcn_mfma_f32_16x16x32_bf16(a, b, acc2[n], 0, 0, 0);
        }
    }
#pragma unroll
    for (int n = 0; n < 4; ++n) {
        int col = wcol + n * 16 + fr;
        float bv = fb[col];
#pragma unroll
        for (int r = 0; r < 4; ++r) {
            int ro = wr + ((lane >> 4) << 2) + r;
            float ov = (float)((__bf16*)ats)[ro * 128 + (col ^ ((ro & 7) << 3))];
            float val = acc2[n][r] + bv + gelu_f(ov);
            out[(size_t)(R + ro) * 128 + col] = val;
            if (Xcur) Xcur[(size_t)(R + ro) * 256 + col] = (__bf16)val;
        }
    }
}

// ---------------------------------------------------------------------------
extern "C" void kernel_launch(void* const* d_in, const int* in_sizes, int n_in,
                              void* d_out, int out_size, void* d_ws, size_t ws_size,
                              hipStream_t stream)
{
    const float* seq       = (const float*)d_in[0];
    const float* Hpre      = (const float*)d_in[1];
    const float* pro1_w    = (const float*)d_in[2];
    const float* pro1_b    = (const float*)d_in[3];
    const float* pro2_w    = (const float*)d_in[4];
    const float* pro2_b    = (const float*)d_in[5];
    const float* ln_cur_s  = (const float*)d_in[6];
    const float* ln_cur_b  = (const float*)d_in[7];
    const float* ln_pre_s  = (const float*)d_in[8];
    const float* ln_pre_b  = (const float*)d_in[9];
    const float* cur_qkv_w = (const float*)d_in[10];
    const float* cur_qkv_b = (const float*)d_in[11];
    const float* pre_qkv_w = (const float*)d_in[12];
    const float* pre_qkv_b = (const float*)d_in[13];
    const float* alpha     = (const float*)d_in[14];
    const float* proj_w    = (const float*)d_in[15];
    const float* proj_b    = (const float*)d_in[16];
    const float* bn1_s     = (const float*)d_in[17];
    const float* bn1_b     = (const float*)d_in[18];
    const float* bn2_s     = (const float*)d_in[19];
    const float* bn2_b     = (const float*)d_in[20];
    const float* ln_o_s    = (const float*)d_in[21];
    const float* ln_o_b    = (const float*)d_in[22];
    const float* ffn_w     = (const float*)d_in[23];
    const float* ffn_b     = (const float*)d_in[24];

    char* ws = (char*)d_ws;
    // bf16 weight caches
    __bf16* Wq      = (__bf16*)ws;                 ws += (size_t)4 * 3072 * 256 * 2;  // 6.29MB
    float*  bq      = (float*)ws;                  ws += (size_t)4 * 3072 * 4;        // 48KB
    __bf16* Wp_bf   = (__bf16*)ws;                 ws += (size_t)4 * 128 * 1024 * 2;  // 1MB
    __bf16* Wf_bf   = (__bf16*)ws;                 ws += (size_t)4 * 128 * 128 * 2;
    __bf16* pro1_bf = (__bf16*)ws;                 ws += (size_t)128 * 128 * 2;
    __bf16* pro2_bf = (__bf16*)ws;                 ws += (size_t)4 * 128 * 128 * 2;
    // activations
    __bf16* X    = (__bf16*)ws;                    ws += (size_t)8192 * 256 * 2;      // [row][0:128]=cur,[128:256]=pre
    float*  cur  = (float*)ws;                     ws += (size_t)8192 * 128 * 4;
    __bf16* Atb  = (__bf16*)ws;                    ws += (size_t)8192 * 1024 * 2;
    __bf16* Qb   = (__bf16*)ws;                    ws += (size_t)8192 * 1024 * 2;
    __bf16* Kb   = (__bf16*)ws;                    ws += (size_t)8192 * 1024 * 2;
    __bf16* Vb   = (__bf16*)ws;                    ws += (size_t)8192 * 1024 * 2;     // transposed (BN,H,F,P)

    // ---- precompute (cheap, every call; deterministic)
    build_wq<<<1536, 256, 0, stream>>>(cur_qkv_w, cur_qkv_b, pre_qkv_w, pre_qkv_b,
                                       alpha, Wq, bq);
    cvt_bf16<<<512, 256, 0, stream>>>(proj_w, Wp_bf, 4 * 128 * 1024);
    cvt_bf16<<<64, 256, 0, stream>>>(ffn_w, Wf_bf, 4 * 128 * 128);
    cvt_bf16<<<16, 256, 0, stream>>>(pro1_w, pro1_bf, 128 * 128);
    cvt_bf16<<<64, 256, 0, stream>>>(pro2_w, pro2_bf, 4 * 128 * 128);

    for (int l = 0; l < 4; ++l) {
        if (l == 0) {
            lin_ln_mfma<<<128, 256, 0, stream>>>(seq, pro1_bf, pro1_b,
                                                 ln_cur_s, ln_cur_b, cur, X);
        }
        lin_ln_mfma<<<128, 256, 0, stream>>>(Hpre + (size_t)l * 8192 * 128,
                                             pro2_bf + (size_t)l * 16384,
                                             pro2_b + l * 128,
                                             ln_pre_s + l * 128, ln_pre_b + l * 128,
                                             nullptr, X + 128);
        qkv_mfma<<<dim3(64, 48), 256, 0, stream>>>(
            X, Wq + (size_t)l * 3072 * 256, bq + l * 3072, Qb, Kb, Vb);
        attn_mfma<<<1024, 256, 0, stream>>>(Qb, Kb, Vb,
                                            bn1_s + l * 128, bn1_b + l * 128, Atb);
        float* outp = (l == 3) ? (float*)d_out : cur;
        proj_ffn_mfma<<<256, 256, 0, stream>>>(Atb,
                                               Wp_bf + (size_t)l * 128 * 1024,
                                               proj_b + l * 128,
                                               bn2_s + l * 128, bn2_b + l * 128,
                                               ln_o_s + l * 128, ln_o_b + l * 128,
                                               Wf_bf + (size_t)l * 16384,
                                               ffn_b + l * 128,
                                               cur, outp, (l == 3) ? nullptr : X);
    }
}

// Round 5
// 298.288 us; speedup vs baseline: 10.6932x; 1.2080x over previous
//
#include <hip/hip_runtime.h>
#include <math.h>

#define EPS 1e-5f

// L=4, B=16, N=8, P=64, D=128, F=128, H=8
// M = B*N*P = 8192 rows, HF = 1024, QKV width = 3072

typedef __bf16 bf16x8 __attribute__((ext_vector_type(8)));
typedef __bf16 bf16x4 __attribute__((ext_vector_type(4)));
typedef float f32x4 __attribute__((ext_vector_type(4)));

__device__ __forceinline__ float gelu_f(float x) {
    return 0.5f * x * (1.0f + erff(x * 0.7071067811865476f));
}

// async 16B global->LDS (linear dest, per-lane source). Dest stride must be
// lane*16B within the wave (rule: wave-uniform base + lane*size).
__device__ __forceinline__ void gll16(const void* g, void* l) {
    __builtin_amdgcn_global_load_lds(
        (const __attribute__((address_space(1))) void*)g,
        (__attribute__((address_space(3))) void*)l, 16, 0, 0);
}

// convert 8 consecutive floats -> 8 bf16, store 16B to (swizzled) LDS slot
__device__ __forceinline__ void cvt_store8(void* dst, const float* __restrict__ src) {
    float4 a = ((const float4*)src)[0];
    float4 b = ((const float4*)src)[1];
    bf16x8 v;
    v[0] = (__bf16)a.x; v[1] = (__bf16)a.y; v[2] = (__bf16)a.z; v[3] = (__bf16)a.w;
    v[4] = (__bf16)b.x; v[5] = (__bf16)b.y; v[6] = (__bf16)b.z; v[7] = (__bf16)b.w;
    *(bf16x8*)dst = v;
}

// 128-wide bf16 tile, XOR swizzle: elem = row*128 + (k ^ ((row&7)<<3))
__device__ __forceinline__ int swz(int row, int k0) {
    return row * 128 + (k0 ^ ((row & 7) << 3));
}
// 64-wide bf16 tile
__device__ __forceinline__ int swz64(int row, int k0) {
    return row * 64 + (k0 ^ ((row & 7) << 3));
}

// ---------------------------------------------------------------------------
// Precompute A: blend-folded QKV weight  W'[l] = [a*Wc | (1-a)*Wp]  (bf16)
// and bias b' = a*bc + (1-a)*bp (f32).
// ---------------------------------------------------------------------------
__global__ __launch_bounds__(256) void build_wq(
    const float* __restrict__ Wc, const float* __restrict__ bc,
    const float* __restrict__ Wp, const float* __restrict__ bp,
    const float* __restrict__ alpha,
    __bf16* __restrict__ Wq, float* __restrict__ bq)
{
    int idx = blockIdx.x * 256 + threadIdx.x;      // [0, 393216)
    int l = idx / 98304, rem = idx - l * 98304;    // 98304 = 3072*32
    int row = rem >> 5, g = rem & 31, k0 = g << 3;
    float a = 1.0f / (1.0f + expf(-alpha[l * 3072 + row]));
    __bf16* dst = Wq + ((size_t)l * 3072 + row) * 256 + k0;
    if (k0 < 128) {
        const float* s = Wc + ((size_t)l * 3072 + row) * 128 + k0;
#pragma unroll
        for (int j = 0; j < 8; ++j) dst[j] = (__bf16)(a * s[j]);
    } else {
        const float* s = Wp + ((size_t)l * 3072 + row) * 128 + (k0 - 128);
#pragma unroll
        for (int j = 0; j < 8; ++j) dst[j] = (__bf16)((1.0f - a) * s[j]);
    }
    if (g == 0)
        bq[l * 3072 + row] = a * bc[l * 3072 + row] + (1.0f - a) * bp[l * 3072 + row];
}

__global__ __launch_bounds__(256) void cvt_bf16(
    const float* __restrict__ src, __bf16* __restrict__ dst, int n)
{
    int i = (blockIdx.x * 256 + threadIdx.x) * 4;
    if (i < n) {
        float4 v = *(const float4*)(src + i);
        dst[i] = (__bf16)v.x; dst[i + 1] = (__bf16)v.y;
        dst[i + 2] = (__bf16)v.z; dst[i + 3] = (__bf16)v.w;
    }
}

// ---------------------------------------------------------------------------
// Kernel 1 (MFMA): y = LN(x @ W^T + b)*s + t.  32-row tile, grid 256.
// ---------------------------------------------------------------------------
__global__ __launch_bounds__(256) void lin_ln_mfma(
    const float* __restrict__ x, const __bf16* __restrict__ Wbf,
    const float* __restrict__ bias, const float* __restrict__ lns,
    const float* __restrict__ lnb,
    float* __restrict__ yf, __bf16* __restrict__ Xout)
{
    __shared__ __align__(16) char lds[40960];
    unsigned short* xs = (unsigned short*)lds;            // [32][128] bf16
    unsigned short* ws = (unsigned short*)(lds + 8192);   // [128][128] bf16
    float* outs = (float*)lds;                            // [32][132] f32 alias
    int t = threadIdx.x;
    int R = blockIdx.x * 32;
#pragma unroll
    for (int i = 0; i < 2; ++i) {
        int c = t + i * 256; int row = c >> 4, k0 = (c & 15) << 3;
        cvt_store8(&xs[swz(row, k0)], x + (size_t)(R + row) * 128 + k0);
    }
#pragma unroll
    for (int i = 0; i < 8; ++i) {
        int c = t + i * 256; int row = c >> 4, k0 = (c & 15) << 3;
        gll16(Wbf + (size_t)row * 128 + (k0 ^ ((row & 7) << 3)), &ws[c * 8]);
    }
    __syncthreads();
    int lane = t & 63, w = t >> 6;
    int wr = (w >> 1) * 16, wcol = (w & 1) * 64;
    int fr = lane & 15, fk = (lane >> 4) << 3;
    f32x4 acc[4] = {};
#pragma unroll
    for (int kk = 0; kk < 4; ++kk) {
        int k0 = kk * 32 + fk;
        bf16x8 a = *(const bf16x8*)&xs[swz(wr + fr, k0)];
#pragma unroll
        for (int n = 0; n < 4; ++n) {
            bf16x8 b = *(const bf16x8*)&ws[swz(wcol + n * 16 + fr, k0)];
            acc[n] = __builtin_amdgcn_mfma_f32_16x16x32_bf16(a, b, acc[n], 0, 0, 0);
        }
    }
    __syncthreads();
#pragma unroll
    for (int n = 0; n < 4; ++n) {
        int col = wcol + n * 16 + fr;
        float bv = bias[col];
        int rl = wr + ((lane >> 4) << 2);
#pragma unroll
        for (int r = 0; r < 4; ++r) outs[(rl + r) * 132 + col] = acc[n][r] + bv;
    }
    __syncthreads();
    int row = t >> 3, oc = t & 7;
    float vals[16]; float s = 0.0f;
#pragma unroll
    for (int i = 0; i < 16; ++i) { vals[i] = outs[row * 132 + oc + 8 * i]; s += vals[i]; }
    s += __shfl_xor(s, 1, 8); s += __shfl_xor(s, 2, 8); s += __shfl_xor(s, 4, 8);
    float mean = s * (1.0f / 128.0f);
    float sq = 0.0f;
#pragma unroll
    for (int i = 0; i < 16; ++i) { float d = vals[i] - mean; sq += d * d; }
    sq += __shfl_xor(sq, 1, 8); sq += __shfl_xor(sq, 2, 8); sq += __shfl_xor(sq, 4, 8);
    float rs = rsqrtf(sq * (1.0f / 128.0f) + EPS);
#pragma unroll
    for (int i = 0; i < 16; ++i) {
        int c = oc + 8 * i;
        float yv = (vals[i] - mean) * rs * lns[c] + lnb[c];
        if (yf) yf[(size_t)(R + row) * 128 + c] = yv;
        Xout[(size_t)(R + row) * 256 + c] = (__bf16)yv;
    }
}

// ---------------------------------------------------------------------------
// Kernel 2 (MFMA, m97-structure): folded QKV GEMM X(8192x256)@Wq(3072x256)^T.
// 128x128 tile, BK=64, 4 waves of 64x64 (4x4 frags). Grid (64,24).
// global_load_lds staging: linear LDS dest + inverse-swizzled source.
// ---------------------------------------------------------------------------
__global__ __launch_bounds__(256) void qkv_mfma(
    const __bf16* __restrict__ X, const __bf16* __restrict__ Wq,
    const float* __restrict__ bq,
    __bf16* __restrict__ Q, __bf16* __restrict__ Kout, __bf16* __restrict__ Vt)
{
    __shared__ __align__(16) unsigned short As[128 * 64];   // 16KB
    __shared__ __align__(16) unsigned short Bs[128 * 64];   // 16KB
    int t = threadIdx.x, lane = t & 63, w = t >> 6;
    int BR = blockIdx.x * 128, BC = blockIdx.y * 128;
    int wrow = (w >> 1) * 64, wcol = (w & 1) * 64;
    int fr = lane & 15, fk = (lane >> 4) << 3;

    f32x4 acc[4][4] = {};
    for (int kc = 0; kc < 4; ++kc) {
#pragma unroll
        for (int i = 0; i < 4; ++i) {
            int c = t + i * 256;                 // [0,1024) 16B chunks
            int row = c >> 3, k0 = (c & 7) << 3;
            int ks = k0 ^ ((row & 7) << 3);
            gll16(X + (size_t)(BR + row) * 256 + kc * 64 + ks, &As[c * 8]);
            gll16(Wq + (size_t)(BC + row) * 256 + kc * 64 + ks, &Bs[c * 8]);
        }
        __syncthreads();
#pragma unroll
        for (int kk = 0; kk < 2; ++kk) {
            int k = kk * 32 + fk;
            bf16x8 a[4], b[4];
#pragma unroll
            for (int m = 0; m < 4; ++m) {
                int r = wrow + m * 16 + fr;
                a[m] = *(const bf16x8*)&As[r * 64 + (k ^ ((r & 7) << 3))];
            }
#pragma unroll
            for (int n = 0; n < 4; ++n) {
                int r = wcol + n * 16 + fr;
                b[n] = *(const bf16x8*)&Bs[r * 64 + (k ^ ((r & 7) << 3))];
            }
#pragma unroll
            for (int m = 0; m < 4; ++m)
#pragma unroll
                for (int n = 0; n < 4; ++n)
                    acc[m][n] = __builtin_amdgcn_mfma_f32_16x16x32_bf16(a[m], b[n], acc[m][n], 0, 0, 0);
        }
        __syncthreads();
    }

    int qt = BC >> 10;          // 0=Q 1=K 2=V, uniform per block
#pragma unroll
    for (int n = 0; n < 4; ++n) {
        int col = BC + wcol + n * 16 + fr;
        int hf = col & 1023, h = hf >> 7, f = hf & 127;
        float bv = bq[col];
#pragma unroll
        for (int m = 0; m < 4; ++m) {
            int rb = BR + wrow + m * 16 + ((lane >> 4) << 2);
            int bn = rb >> 6, p0 = rb & 63;
            if (qt == 2) {
                bf16x4 pk;
#pragma unroll
                for (int r = 0; r < 4; ++r) pk[r] = (__bf16)(acc[m][n][r] + bv);
                *(bf16x4*)&Vt[(size_t)((bn * 8 + h) * 128 + f) * 64 + p0] = pk;
            } else {
                __bf16* dst = (qt == 1) ? Kout : Q;
#pragma unroll
                for (int r = 0; r < 4; ++r)
                    dst[(size_t)((bn * 8 + h) * 64 + p0 + r) * 128 + f] =
                        (__bf16)(acc[m][n][r] + bv);
            }
        }
    }
}

// ---------------------------------------------------------------------------
// Kernel 3 (MFMA): attention per (b,n,h) + bn1 LN -> At bf16 (B,N,P,H*F).
// ---------------------------------------------------------------------------
__global__ __launch_bounds__(256) void attn_mfma(
    const __bf16* __restrict__ Q, const __bf16* __restrict__ K,
    const __bf16* __restrict__ Vt,
    const float* __restrict__ bn1s, const float* __restrict__ bn1b,
    __bf16* __restrict__ At)
{
    int g = blockIdx.x;             // bn*8 + h
    int bn = g >> 3, h = g & 7;
    const __bf16* Qg = Q + (size_t)g * 8192;
    const __bf16* Kg = K + (size_t)g * 8192;
    const __bf16* Vg = Vt + (size_t)g * 8192;   // [128 f][64 p]
    __shared__ __align__(16) unsigned short Ks[64 * 128];
    __shared__ __align__(16) unsigned short Vs[128 * 64];
    __shared__ __align__(16) unsigned short Ps[64 * 64];
    int t = threadIdx.x;
#pragma unroll
    for (int i = 0; i < 4; ++i) {
        int c = t + i * 256;                    // [0,1024)
        int row = c >> 4, k0 = (c & 15) << 3;
        gll16(Kg + (size_t)row * 128 + (k0 ^ ((row & 7) << 3)), &Ks[c * 8]);
        int rv = c >> 3, kv = (c & 7) << 3;
        gll16(Vg + (size_t)rv * 64 + (kv ^ ((rv & 7) << 3)), &Vs[c * 8]);
    }
    __syncthreads();

    int lane = t & 63, w = t >> 6;
    int w16 = w * 16;
    int fr = lane & 15, fk = (lane >> 4) << 3;

    // --- QK^T: Q fragments direct from global (bf16)
    const __bf16* qbase = Qg + (size_t)(w16 + fr) * 128;
    f32x4 sacc[4] = {};
#pragma unroll
    for (int kk = 0; kk < 4; ++kk) {
        int k0 = kk * 32 + fk;
        bf16x8 aq = *(const bf16x8*)(qbase + k0);
#pragma unroll
        for (int n = 0; n < 4; ++n) {
            bf16x8 bk = *(const bf16x8*)&Ks[swz(n * 16 + fr, k0)];
            sacc[n] = __builtin_amdgcn_mfma_f32_16x16x32_bf16(aq, bk, sacc[n], 0, 0, 0);
        }
    }

    const float scale = 0.08838834764831845f;   // 128^-0.5
#pragma unroll
    for (int r = 0; r < 4; ++r) {
        float sv[4];
#pragma unroll
        for (int n = 0; n < 4; ++n) sv[n] = sacc[n][r] * scale;
        float mx = fmaxf(fmaxf(sv[0], sv[1]), fmaxf(sv[2], sv[3]));
        mx = fmaxf(mx, __shfl_xor(mx, 1, 16));
        mx = fmaxf(mx, __shfl_xor(mx, 2, 16));
        mx = fmaxf(mx, __shfl_xor(mx, 4, 16));
        mx = fmaxf(mx, __shfl_xor(mx, 8, 16));
        float sum = 0.0f;
#pragma unroll
        for (int n = 0; n < 4; ++n) { sv[n] = expf(sv[n] - mx); sum += sv[n]; }
        sum += __shfl_xor(sum, 1, 16);
        sum += __shfl_xor(sum, 2, 16);
        sum += __shfl_xor(sum, 4, 16);
        sum += __shfl_xor(sum, 8, 16);
        float inv = 1.0f / sum;
        int p = w16 + ((lane >> 4) << 2) + r;
#pragma unroll
        for (int n = 0; n < 4; ++n) {
            int q = n * 16 + fr;
            ((__bf16*)Ps)[p * 64 + (q ^ ((p & 7) << 3))] = (__bf16)(sv[n] * inv);
        }
    }
    __syncthreads();

    // --- PV
    f32x4 oacc[8] = {};
#pragma unroll
    for (int kk = 0; kk < 2; ++kk) {
        int k0 = kk * 32 + fk;
        bf16x8 ap = *(const bf16x8*)&Ps[swz64(w16 + fr, k0)];
#pragma unroll
        for (int n = 0; n < 8; ++n) {
            bf16x8 bv = *(const bf16x8*)&Vs[swz64(n * 16 + fr, k0)];
            oacc[n] = __builtin_amdgcn_mfma_f32_16x16x32_bf16(ap, bv, oacc[n], 0, 0, 0);
        }
    }

    // --- bn1 LN over f + transposed bf16 write
#pragma unroll
    for (int r = 0; r < 4; ++r) {
        int p = w16 + ((lane >> 4) << 2) + r;
        float s1 = 0.0f;
#pragma unroll
        for (int n = 0; n < 8; ++n) s1 += oacc[n][r];
        s1 += __shfl_xor(s1, 1, 16);
        s1 += __shfl_xor(s1, 2, 16);
        s1 += __shfl_xor(s1, 4, 16);
        s1 += __shfl_xor(s1, 8, 16);
        float mean = s1 * (1.0f / 128.0f);
        float s2 = 0.0f;
#pragma unroll
        for (int n = 0; n < 8; ++n) { float d = oacc[n][r] - mean; s2 += d * d; }
        s2 += __shfl_xor(s2, 1, 16);
        s2 += __shfl_xor(s2, 2, 16);
        s2 += __shfl_xor(s2, 4, 16);
        s2 += __shfl_xor(s2, 8, 16);
        float rs = rsqrtf(s2 * (1.0f / 128.0f) + EPS);
        __bf16* orow = At + (size_t)(bn * 64 + p) * 1024 + h * 128;
#pragma unroll
        for (int n = 0; n < 8; ++n) {
            int f = n * 16 + fr;
            orow[f] = (__bf16)((oacc[n][r] - mean) * rs * bn1s[f] + bn1b[f]);
        }
    }
}

// ---------------------------------------------------------------------------
// Kernel 4 (MFMA): proj (K=1024) + bn2 LN + gelu(cur) residual + ln_o LN
// + ffn GEMM + gelu(O_hat).  32-row tile, grid 256.
// ---------------------------------------------------------------------------
__global__ __launch_bounds__(256) void proj_ffn_mfma(
    const __bf16* __restrict__ At_g, const __bf16* __restrict__ Wp,
    const float* __restrict__ pb,
    const float* __restrict__ bn2s, const float* __restrict__ bn2b,
    const float* __restrict__ lnos, const float* __restrict__ lnob,
    const __bf16* __restrict__ Wf, const float* __restrict__ fb,
    const float* __restrict__ cur, float* __restrict__ out,
    __bf16* __restrict__ Xcur)
{
    __shared__ __align__(16) char lds[40960];
    unsigned short* ats = (unsigned short*)lds;           // [32][128] bf16
    unsigned short* wts = (unsigned short*)(lds + 8192);  // [128][128] bf16
    float* outs = (float*)lds;                            // [32][132] f32 alias
    int t = threadIdx.x;
    int R = blockIdx.x * 32;
    int lane = t & 63, w = t >> 6;
    int wr = (w >> 1) * 16, wcol = (w & 1) * 64;
    int fr = lane & 15, fk = (lane >> 4) << 3;

    // ---- phase 1: proj GEMM over 8 K-chunks
    f32x4 acc[4] = {};
    for (int kc = 0; kc < 8; ++kc) {
#pragma unroll
        for (int i = 0; i < 2; ++i) {
            int c = t + i * 256; int row = c >> 4, k0 = (c & 15) << 3;
            gll16(At_g + (size_t)(R + row) * 1024 + kc * 128 + (k0 ^ ((row & 7) << 3)),
                  &ats[c * 8]);
        }
#pragma unroll
        for (int i = 0; i < 8; ++i) {
            int c = t + i * 256; int row = c >> 4, k0 = (c & 15) << 3;
            gll16(Wp + (size_t)row * 1024 + kc * 128 + (k0 ^ ((row & 7) << 3)),
                  &wts[c * 8]);
        }
        __syncthreads();
#pragma unroll
        for (int kk = 0; kk < 4; ++kk) {
            int k0 = kk * 32 + fk;
            bf16x8 a = *(const bf16x8*)&ats[swz(wr + fr, k0)];
#pragma unroll
            for (int n = 0; n < 4; ++n) {
                bf16x8 b = *(const bf16x8*)&wts[swz(wcol + n * 16 + fr, k0)];
                acc[n] = __builtin_amdgcn_mfma_f32_16x16x32_bf16(a, b, acc[n], 0, 0, 0);
            }
        }
        __syncthreads();
    }

#pragma unroll
    for (int n = 0; n < 4; ++n) {
        int col = wcol + n * 16 + fr;
        float bv = pb[col];
        int rl = wr + ((lane >> 4) << 2);
#pragma unroll
        for (int r = 0; r < 4; ++r) outs[(rl + r) * 132 + col] = acc[n][r] + bv;
    }
    __syncthreads();

    // ---- phase 2: bn2 LN -> +gelu(cur) residual -> ln_o LN (8 lanes/row)
    int row = t >> 3, oc = t & 7;
    float vals[16]; float s = 0.0f;
#pragma unroll
    for (int i = 0; i < 16; ++i) { vals[i] = outs[row * 132 + oc + 8 * i]; s += vals[i]; }
    s += __shfl_xor(s, 1, 8); s += __shfl_xor(s, 2, 8); s += __shfl_xor(s, 4, 8);
    float mean = s * (1.0f / 128.0f);
    float sq = 0.0f;
#pragma unroll
    for (int i = 0; i < 16; ++i) { float d = vals[i] - mean; sq += d * d; }
    sq += __shfl_xor(sq, 1, 8); sq += __shfl_xor(sq, 2, 8); sq += __shfl_xor(sq, 4, 8);
    float rs = rsqrtf(sq * (1.0f / 128.0f) + EPS);

    float oh[16]; float s2 = 0.0f;
#pragma unroll
    for (int i = 0; i < 16; ++i) {
        int c = oc + 8 * i;
        float ynorm = (vals[i] - mean) * rs * bn2s[c] + bn2b[c];
        float cv = cur[(size_t)(R + row) * 128 + c];
        oh[i] = cv + (ynorm + gelu_f(cv));
        s2 += oh[i];
    }
    s2 += __shfl_xor(s2, 1, 8); s2 += __shfl_xor(s2, 2, 8); s2 += __shfl_xor(s2, 4, 8);
    float mean2 = s2 * (1.0f / 128.0f);
    float sq2 = 0.0f;
#pragma unroll
    for (int i = 0; i < 16; ++i) { float d = oh[i] - mean2; sq2 += d * d; }
    sq2 += __shfl_xor(sq2, 1, 8); sq2 += __shfl_xor(sq2, 2, 8); sq2 += __shfl_xor(sq2, 4, 8);
    float rs2 = rsqrtf(sq2 * (1.0f / 128.0f) + EPS);
#pragma unroll
    for (int i = 0; i < 16; ++i) {
        int c = oc + 8 * i;
        oh[i] = (oh[i] - mean2) * rs2 * lnos[c] + lnob[c];   // O_hat
    }
    __syncthreads();

    // ---- phase 3: stage O_hat (bf16) + Wf, ffn GEMM + gelu epilogue
#pragma unroll
    for (int i = 0; i < 16; ++i) {
        int c = oc + 8 * i;
        ((__bf16*)ats)[row * 128 + (c ^ ((row & 7) << 3))] = (__bf16)oh[i];
    }
#pragma unroll
    for (int i = 0; i < 8; ++i) {
        int c = t + i * 256; int rw = c >> 4, k0 = (c & 15) << 3;
        gll16(Wf + (size_t)rw * 128 + (k0 ^ ((rw & 7) << 3)), &wts[c * 8]);
    }
    __syncthreads();

    f32x4 acc2[4] = {};
#pragma unroll
    for (int kk = 0; kk < 4; ++kk) {
        int k0 = kk * 32 + fk;
        bf16x8 a = *(const bf16x8*)&ats[swz(wr + fr, k0)];
#pragma unroll
        for (int n = 0; n < 4; ++n) {
            bf16x8 b = *(const bf16x8*)&wts[swz(wcol + n * 16 + fr, k0)];
            acc2[n] = __builtin_amdgcn_mfma_f32_16x16x32_bf16(a, b, acc2[n], 0, 0, 0);
        }
    }
#pragma unroll
    for (int n = 0; n < 4; ++n) {
        int col = wcol + n * 16 + fr;
        float bv = fb[col];
#pragma unroll
        for (int r = 0; r < 4; ++r) {
            int ro = wr + ((lane >> 4) << 2) + r;
            float ov = (float)((__bf16*)ats)[ro * 128 + (col ^ ((ro & 7) << 3))];
            float val = acc2[n][r] + bv + gelu_f(ov);
            out[(size_t)(R + ro) * 128 + col] = val;
            if (Xcur) Xcur[(size_t)(R + ro) * 256 + col] = (__bf16)val;
        }
    }
}

// ---------------------------------------------------------------------------
extern "C" void kernel_launch(void* const* d_in, const int* in_sizes, int n_in,
                              void* d_out, int out_size, void* d_ws, size_t ws_size,
                              hipStream_t stream)
{
    const float* seq       = (const float*)d_in[0];
    const float* Hpre      = (const float*)d_in[1];
    const float* pro1_w    = (const float*)d_in[2];
    const float* pro1_b    = (const float*)d_in[3];
    const float* pro2_w    = (const float*)d_in[4];
    const float* pro2_b    = (const float*)d_in[5];
    const float* ln_cur_s  = (const float*)d_in[6];
    const float* ln_cur_b  = (const float*)d_in[7];
    const float* ln_pre_s  = (const float*)d_in[8];
    const float* ln_pre_b  = (const float*)d_in[9];
    const float* cur_qkv_w = (const float*)d_in[10];
    const float* cur_qkv_b = (const float*)d_in[11];
    const float* pre_qkv_w = (const float*)d_in[12];
    const float* pre_qkv_b = (const float*)d_in[13];
    const float* alpha     = (const float*)d_in[14];
    const float* proj_w    = (const float*)d_in[15];
    const float* proj_b    = (const float*)d_in[16];
    const float* bn1_s     = (const float*)d_in[17];
    const float* bn1_b     = (const float*)d_in[18];
    const float* bn2_s     = (const float*)d_in[19];
    const float* bn2_b     = (const float*)d_in[20];
    const float* ln_o_s    = (const float*)d_in[21];
    const float* ln_o_b    = (const float*)d_in[22];
    const float* ffn_w     = (const float*)d_in[23];
    const float* ffn_b     = (const float*)d_in[24];

    char* ws = (char*)d_ws;
    __bf16* Wq      = (__bf16*)ws;                 ws += (size_t)4 * 3072 * 256 * 2;
    float*  bq      = (float*)ws;                  ws += (size_t)4 * 3072 * 4;
    __bf16* Wp_bf   = (__bf16*)ws;                 ws += (size_t)4 * 128 * 1024 * 2;
    __bf16* Wf_bf   = (__bf16*)ws;                 ws += (size_t)4 * 128 * 128 * 2;
    __bf16* pro1_bf = (__bf16*)ws;                 ws += (size_t)128 * 128 * 2;
    __bf16* pro2_bf = (__bf16*)ws;                 ws += (size_t)4 * 128 * 128 * 2;
    __bf16* X    = (__bf16*)ws;                    ws += (size_t)8192 * 256 * 2;
    float*  cur  = (float*)ws;                     ws += (size_t)8192 * 128 * 4;
    __bf16* Atb  = (__bf16*)ws;                    ws += (size_t)8192 * 1024 * 2;
    __bf16* Qb   = (__bf16*)ws;                    ws += (size_t)8192 * 1024 * 2;
    __bf16* Kb   = (__bf16*)ws;                    ws += (size_t)8192 * 1024 * 2;
    __bf16* Vb   = (__bf16*)ws;                    ws += (size_t)8192 * 1024 * 2;

    build_wq<<<1536, 256, 0, stream>>>(cur_qkv_w, cur_qkv_b, pre_qkv_w, pre_qkv_b,
                                       alpha, Wq, bq);
    cvt_bf16<<<512, 256, 0, stream>>>(proj_w, Wp_bf, 4 * 128 * 1024);
    cvt_bf16<<<64, 256, 0, stream>>>(ffn_w, Wf_bf, 4 * 128 * 128);
    cvt_bf16<<<16, 256, 0, stream>>>(pro1_w, pro1_bf, 128 * 128);
    cvt_bf16<<<64, 256, 0, stream>>>(pro2_w, pro2_bf, 4 * 128 * 128);

    for (int l = 0; l < 4; ++l) {
        if (l == 0) {
            lin_ln_mfma<<<256, 256, 0, stream>>>(seq, pro1_bf, pro1_b,
                                                 ln_cur_s, ln_cur_b, cur, X);
        }
        lin_ln_mfma<<<256, 256, 0, stream>>>(Hpre + (size_t)l * 8192 * 128,
                                             pro2_bf + (size_t)l * 16384,
                                             pro2_b + l * 128,
                                             ln_pre_s + l * 128, ln_pre_b + l * 128,
                                             nullptr, X + 128);
        qkv_mfma<<<dim3(64, 24), 256, 0, stream>>>(
            X, Wq + (size_t)l * 3072 * 256, bq + l * 3072, Qb, Kb, Vb);
        attn_mfma<<<1024, 256, 0, stream>>>(Qb, Kb, Vb,
                                            bn1_s + l * 128, bn1_b + l * 128, Atb);
        float* outp = (l == 3) ? (float*)d_out : cur;
        proj_ffn_mfma<<<256, 256, 0, stream>>>(Atb,
                                               Wp_bf + (size_t)l * 128 * 1024,
                                               proj_b + l * 128,
                                               bn2_s + l * 128, bn2_b + l * 128,
                                               ln_o_s + l * 128, ln_o_b + l * 128,
                                               Wf_bf + (size_t)l * 16384,
                                               ffn_b + l * 128,
                                               cur, outp, (l == 3) ? nullptr : X);
    }
}